// Round 7
// baseline (241.495 us; speedup 1.0000x reference)
//
#include <hip/hip_runtime.h>
#include <hip/hip_bf16.h>

typedef __hip_bfloat16 bf16;
typedef short short8v __attribute__((ext_vector_type(8)));
typedef short short4v __attribute__((ext_vector_type(4)));
typedef float floatx4 __attribute__((ext_vector_type(4)));

#define HW 16384

__device__ __forceinline__ float b2f(bf16 v) { return __bfloat162float(v); }
__device__ __forceinline__ bf16 f2b(float v) { return __float2bfloat16(v); }
__device__ __forceinline__ short f2bs(float v) { bf16 h = __float2bfloat16(v); return __builtin_bit_cast(short, h); }
__device__ __forceinline__ float bs2f(short s) { return b2f(__builtin_bit_cast(bf16, s)); }
__device__ __forceinline__ int wuniform(int v) { return __builtin_amdgcn_readfirstlane(v); }

// ---- ws byte offsets (total 41 MiB, proven safe) ----
// xp is 512 KB: [0, 524288). NOTHING else may live below OFFB_K2 (R6 lesson: alias -> NaN).
#define OFFB_XP    0u
#define OFFB_K2    524288u            // after k_attn: bf16 weights (Wproj@0, Wa1@16384, Wa2@20480 shorts)
#define OFFB_V2    786432u
#define OFFB_QKVG  (1u << 20)         // bf16 (b,256,HW): 0-63 q, 64-127 k, 128-191 v, 192-255 qg->res_l
#define OFFB_RESH  (33u << 20)        // bf16 (b,64,HW); first 64KB = conv weights bf16 until k_resh
// p / v-hat scratch in d_out [0,16MiB); d_out fully overwritten by k_proj.

// ---------------- 8x8 avgpool + conv-weight bf16 preconvert (blocks 0-7) ----------------
__global__ __launch_bounds__(256) void k_pool(const float* __restrict__ x, float* __restrict__ xp,
                                              const float* __restrict__ Wqkv, const float* __restrict__ Wq,
                                              short* __restrict__ wconv)
{
    int idx = blockIdx.x * 256 + threadIdx.x;
    int j = idx & 15, i = (idx >> 4) & 15, bc = idx >> 8;
    const float* src = x + (size_t)bc * HW + (i * 8) * 128 + j * 8;
    float s = 0.f;
    #pragma unroll
    for (int u = 0; u < 8; u++) {
        #pragma unroll
        for (int t = 0; t < 8; t++) s += src[u * 128 + t];
    }
    xp[bc * 256 + i * 16 + j] = s * (1.f / 64.f);

    if (blockIdx.x < 8) {               // convert 32768 conv-weight floats -> bf16 (256x128 row-major)
        int base = blockIdx.x * 4096 + threadIdx.x * 16;
        #pragma unroll
        for (int e = 0; e < 16; e += 4) {
            int k = base + e;
            const float* ws = (k < 24576) ? (Wqkv + k) : (Wq + k - 24576);
            floatx4 wv = *(const floatx4*)ws;
            short4v pk;
            pk[0] = f2bs(wv[0]); pk[1] = f2bs(wv[1]); pk[2] = f2bs(wv[2]); pk[3] = f2bs(wv[3]);
            *(short4v*)&wconv[k] = pk;
        }
    }
}

// ---------------- kv conv: xp -> k2/v2 fp32 (b,h,m,d) ----------------
__global__ __launch_bounds__(256) void k_kv(const float* __restrict__ xp,
                                            const float* __restrict__ Wkv, const float* __restrict__ bkv,
                                            float* __restrict__ k2, float* __restrict__ v2)
{
    int og = blockIdx.x & 15, b = blockIdx.x >> 4;
    int m = threadIdx.x;
    float xr[128];
    #pragma unroll
    for (int c = 0; c < 128; c++) xr[c] = xp[(b * 128 + c) * 256 + m];
    #pragma unroll 1
    for (int t = 0; t < 8; t++) {
        int o = og * 8 + t;
        const float* w = Wkv + o * 128;
        float s0 = 0.f, s1 = 0.f, s2 = 0.f, s3 = 0.f;
        #pragma unroll
        for (int c = 0; c < 128; c += 4) {
            s0 += w[c] * xr[c]; s1 += w[c + 1] * xr[c + 1];
            s2 += w[c + 2] * xr[c + 2]; s3 += w[c + 3] * xr[c + 3];
        }
        float a = bkv[o] + ((s0 + s1) + (s2 + s3));
        int sb = o >> 6, r = o & 63, gh = r >> 4, dh = r & 15;
        float* dst = sb == 0 ? k2 : v2;
        dst[((b * 4 + gh) * 256 + m) * 16 + dh] = a;
    }
}

// ------- MFMA conv1x1: x -> qkvg bf16. grid (64 px-pairs, 2 m-blocks, 4 b); 2 subtiles ---
// B staging conflict-free: thread owns one px (t&127), gathers 8 consecutive channels
// (coalesced dword loads), writes ONE contiguous ds_write_b128 into the packed slot.
__global__ __launch_bounds__(256) void k_conv(const float* __restrict__ x,
                                              const short* __restrict__ wconv,
                                              const float* __restrict__ bqkv, const float* __restrict__ bq,
                                              bf16* __restrict__ qkvg)
{
    __shared__ short a_s[128 * 128];          // A[oc][k] bf16
    __shared__ short b_s[128 * 128];          // B packed [k>>3][px][k&7] bf16
    __shared__ float bias_s[128];
    int t = threadIdx.x;
    int b = blockIdx.z, my = blockIdx.y;
    int px0b = blockIdx.x * 256;

    if (t < 128) {
        int oc = my * 128 + t;
        bias_s[t] = (oc < 192) ? bqkv[oc] : bq[oc - 192];
    }
    const short* wsrc = wconv + my * 16384;   // rows my*128..my*128+127, row-major
    #pragma unroll
    for (int i = 0; i < 8; i++) {             // stage A: bf16 copy
        int idx = i * 2048 + t * 8;
        *(short8v*)&a_s[idx] = *(const short8v*)&wsrc[idx];
    }

    int wave = wuniform(t >> 6);
    int lane = t & 63;
    int quad = lane >> 4, l16 = lane & 15;
    int pxs = t & 127, chalf = (t >> 7) * 64;

    #pragma unroll 1
    for (int sub = 0; sub < 2; sub++) {
        int px0 = px0b + sub * 128;
        const float* xb = x + (size_t)b * 128 * HW + px0 + pxs;
        #pragma unroll
        for (int p = 0; p < 8; p++) {         // stage B: 8 coalesced loads -> 1 b128 write
            int c0 = chalf + p * 8;
            float xv[8];
            #pragma unroll
            for (int jj = 0; jj < 8; jj++) xv[jj] = xb[(size_t)(c0 + jj) * HW];
            short8v pk;
            #pragma unroll
            for (int jj = 0; jj < 8; jj++) pk[jj] = f2bs(xv[jj]);
            *(short8v*)&b_s[((c0 >> 3) * 128 + pxs) * 8] = pk;
        }
        __syncthreads();

        floatx4 acc[2][8] = {};
        #pragma unroll
        for (int kk = 0; kk < 4; kk++) {
            short8v a0 = *(const short8v*)&a_s[(wave * 32 + l16) * 128 + kk * 32 + quad * 8];
            short8v a1 = *(const short8v*)&a_s[(wave * 32 + 16 + l16) * 128 + kk * 32 + quad * 8];
            #pragma unroll
            for (int nt = 0; nt < 8; nt++) {
                short8v bv = *(const short8v*)&b_s[((kk * 4 + quad) * 128 + nt * 16 + l16) * 8];
                acc[0][nt] = __builtin_amdgcn_mfma_f32_16x16x32_bf16(a0, bv, acc[0][nt], 0, 0, 0);
                acc[1][nt] = __builtin_amdgcn_mfma_f32_16x16x32_bf16(a1, bv, acc[1][nt], 0, 0, 0);
            }
        }
        #pragma unroll
        for (int m = 0; m < 2; m++) {
            int rowb = wave * 32 + m * 16 + quad * 4;
            #pragma unroll
            for (int nt = 0; nt < 8; nt++) {
                int px = px0 + nt * 16 + l16;
                #pragma unroll
                for (int r = 0; r < 4; r++) {
                    int row = rowb + r;
                    float val = acc[m][nt][r] + bias_s[row];
                    qkvg[((size_t)b * 256 + my * 128 + row) * HW + px] = f2b(val);
                }
            }
        }
        __syncthreads();                      // MFMA reads done before next-sub B restage
    }
}

// ---------------- depthwise 3x3 + q*k, vectorized: 8 px/thread. grid 2048 ----------------
__global__ __launch_bounds__(256) void k_dw(const bf16* __restrict__ qkvg,
                                            const float* __restrict__ Wdw, const float* __restrict__ bdw,
                                            bf16* __restrict__ p, bf16* __restrict__ v)
{
    int blk = blockIdx.x;            // 2048
    int bc = blk >> 3;               // b*64+c
    int c = bc & 63, b = bc >> 6;
    int g = (blk & 7) * 256 + threadIdx.x;   // 0..2047 pixel-groups in plane
    int i = g >> 4;                  // row
    int j0 = (g & 15) * 8;           // col start
    float acc[3][8];
    #pragma unroll
    for (int pl = 0; pl < 3; pl++) {
        float bias = bdw[pl * 64 + c];
        #pragma unroll
        for (int t2 = 0; t2 < 8; t2++) acc[pl][t2] = bias;
    }
    #pragma unroll
    for (int pl = 0; pl < 3; pl++) {
        const bf16* plane = qkvg + (size_t)(b * 256 + pl * 64 + c) * HW;
        const float* w = Wdw + (pl * 64 + c) * 9;
        #pragma unroll
        for (int dy = 0; dy < 3; dy++) {
            int ii = i + dy - 1;
            float e[10];
            if ((unsigned)ii < 128u) {
                const bf16* r = plane + ii * 128 + j0;
                short8v v8 = *(const short8v*)r;
                #pragma unroll
                for (int t2 = 0; t2 < 8; t2++) e[t2 + 1] = bs2f(v8[t2]);
                e[0] = (j0 > 0) ? b2f(r[-1]) : 0.f;
                e[9] = (j0 < 120) ? b2f(r[8]) : 0.f;
            } else {
                #pragma unroll
                for (int t2 = 0; t2 < 10; t2++) e[t2] = 0.f;
            }
            float wa = w[dy * 3], wb = w[dy * 3 + 1], wc = w[dy * 3 + 2];
            #pragma unroll
            for (int t2 = 0; t2 < 8; t2++)
                acc[pl][t2] += wa * e[t2] + wb * e[t2 + 1] + wc * e[t2 + 2];
        }
    }
    short8v pv, vv;
    #pragma unroll
    for (int t2 = 0; t2 < 8; t2++) {
        pv[t2] = f2bs(acc[0][t2] * acc[1][t2]);
        vv[t2] = f2bs(acc[2][t2]);
    }
    size_t off = (size_t)(b * 64 + c) * HW + i * 128 + j0;
    *(short8v*)(p + off) = pv;
    *(short8v*)(v + off) = vv;
}

// ---------------- MFMA low-freq attention. grid (64 px-blocks, 4 h, 4 b) ----------------
// In-register P (proven R4): key-permuted K staging aligns QK C-layout with PV B-frag
// slots; P stays in VGPRs (clamp -> exp2 -> f2bs -> PV MFMA). LDS 40 KiB, 4 blocks/CU.
__global__ __launch_bounds__(256, 4) void k_attn(bf16* __restrict__ qkvg, const float* __restrict__ k2,
                                                 const float* __restrict__ v2)
{
    __shared__ short kt[16 * 64 * 8];   // 16 KiB: K A-frags (key-permuted), k=16..31 zero
    __shared__ short vt[8 * 64 * 8];    // 8 KiB: V frags (A-role: V^T)
    __shared__ short un[16 * 64 * 8];   // 16 KiB: Q B-frag staging
    int t = threadIdx.x;
    int h = blockIdx.y, b = blockIdx.z;
    int px0b = blockIdx.x * 256;
    const float* K = k2 + (size_t)(b * 4 + h) * 4096;
    const float* V = v2 + (size_t)(b * 4 + h) * 4096;
    bf16* Qbase = qkvg + (size_t)(b * 256 + 192 + h * 16) * HW + px0b;

    {
        int mb = t >> 5, kl = t & 31, q = kl >> 3, s = kl & 7;
        int tile = 2 * mb + (s >> 2), row = q * 4 + (s & 3);
        float4 k0 = *(const float4*)(K + t * 16);
        float4 k1 = *(const float4*)(K + t * 16 + 4);
        float4 kx2 = *(const float4*)(K + t * 16 + 8);
        float4 k3 = *(const float4*)(K + t * 16 + 12);
        short8v lo, hi, zz = {};
        lo[0] = f2bs(k0.x); lo[1] = f2bs(k0.y); lo[2] = f2bs(k0.z); lo[3] = f2bs(k0.w);
        lo[4] = f2bs(k1.x); lo[5] = f2bs(k1.y); lo[6] = f2bs(k1.z); lo[7] = f2bs(k1.w);
        hi[0] = f2bs(kx2.x); hi[1] = f2bs(kx2.y); hi[2] = f2bs(kx2.z); hi[3] = f2bs(kx2.w);
        hi[4] = f2bs(k3.x); hi[5] = f2bs(k3.y); hi[6] = f2bs(k3.z); hi[7] = f2bs(k3.w);
        *(short8v*)&kt[(tile * 64 + row) * 8] = lo;
        *(short8v*)&kt[(tile * 64 + 16 + row) * 8] = hi;
        *(short8v*)&kt[(tile * 64 + 32 + row) * 8] = zz;
        *(short8v*)&kt[(tile * 64 + 48 + row) * 8] = zz;
    }
    #pragma unroll
    for (int u = 0; u < 2; u++) {
        int f = t * 2 + u;
        int mb = f >> 6, lane = f & 63, quad = lane >> 4, d = lane & 15;
        short8v pk;
        #pragma unroll
        for (int i = 0; i < 8; i++) pk[i] = f2bs(V[(mb * 32 + quad * 8 + i) * 16 + d]);
        *(short8v*)&vt[f * 8] = pk;
    }
    #pragma unroll
    for (int u = 0; u < 4; u++) {
        int f = t * 4 + u;
        int pxt = f >> 6, lane = f & 63, quad = lane >> 4, l16 = lane & 15;
        int px = pxt * 16 + l16;
        short8v pk = {};
        if (quad < 2) {
            #pragma unroll
            for (int i = 0; i < 8; i++)   // 0.25 (= dh^-0.5) * log2(e) folded in
                pk[i] = f2bs(b2f(Qbase[(size_t)(quad * 8 + i) * HW + px]) * 0.36067376022224085f);
        }
        *(short8v*)&un[f * 8] = pk;
    }
    __syncthreads();

    int wave = wuniform(t >> 6);
    int lane = t & 63;
    int quad = lane >> 4, l16 = lane & 15;
    short8v qf[4];
    #pragma unroll
    for (int u = 0; u < 4; u++)
        qf[u] = *(const short8v*)&un[((wave * 4 + u) * 64 + lane) * 8];

    #pragma unroll
    for (int u = 0; u < 4; u++) {
        int pxt = wave * 4 + u;
        floatx4 denv = {};
        floatx4 oa = {};
        #pragma unroll
        for (int mb = 0; mb < 8; mb++) {
            short8v kfE = *(const short8v*)&kt[((2 * mb) * 64 + lane) * 8];
            short8v kfO = *(const short8v*)&kt[((2 * mb + 1) * 64 + lane) * 8];
            floatx4 scE = __builtin_amdgcn_mfma_f32_16x16x32_bf16(kfE, qf[u], (floatx4){0.f, 0.f, 0.f, 0.f}, 0, 0, 0);
            floatx4 scO = __builtin_amdgcn_mfma_f32_16x16x32_bf16(kfO, qf[u], (floatx4){0.f, 0.f, 0.f, 0.f}, 0, 0, 0);
            floatx4 peE, peO;
            #pragma unroll
            for (int r = 0; r < 4; r++) {
                peE[r] = exp2f(fminf(scE[r], 86.f));
                peO[r] = exp2f(fminf(scO[r], 86.f));
            }
            denv += peE;
            denv += peO;
            short8v pa;
            pa[0] = f2bs(peE[0]); pa[1] = f2bs(peE[1]); pa[2] = f2bs(peE[2]); pa[3] = f2bs(peE[3]);
            pa[4] = f2bs(peO[0]); pa[5] = f2bs(peO[1]); pa[6] = f2bs(peO[2]); pa[7] = f2bs(peO[3]);
            short8v vf = *(const short8v*)&vt[(mb * 64 + lane) * 8];
            oa = __builtin_amdgcn_mfma_f32_16x16x32_bf16(vf, pa, oa, 0, 0, 0);
        }
        float den = (denv[0] + denv[1]) + (denv[2] + denv[3]);
        den += __shfl_xor(den, 16, 64);
        den += __shfl_xor(den, 32, 64);
        float rden = 1.f / den;
        #pragma unroll
        for (int r = 0; r < 4; r++)
            Qbase[(size_t)(quad * 4 + r) * HW + pxt * 16 + l16] = f2b(oa[r] * rden);
    }
}

// ---------------- late-weight bf16 preconvert: Wproj/Wa1/Wa2 -> k2 region (dead) ---------
__global__ __launch_bounds__(256) void k_wcvt(const float* __restrict__ Wproj,
                                              const float* __restrict__ Wa1, const float* __restrict__ Wa2,
                                              short* __restrict__ wdst)
{
    int idx = blockIdx.x * 1024 + threadIdx.x * 4;   // 24 blocks -> 24576 floats
    const float* src;
    if (idx < 16384)      src = Wproj + idx;
    else if (idx < 20480) src = Wa1 + (idx - 16384);
    else                  src = Wa2 + (idx - 20480);
    floatx4 wv = *(const floatx4*)src;
    short4v pk;
    pk[0] = f2bs(wv[0]); pk[1] = f2bs(wv[1]); pk[2] = f2bs(wv[2]); pk[3] = f2bs(wv[3]);
    *(short4v*)&wdst[idx] = pk;
}

// ---------------- MFMA high-freq gate: p,v-hat -> res_h. grid (128 px-tiles, 4 b) --------
// GEMM1 (Wa1 64x64 · P) -> swish -> repack -> GEMM2 (Wa2 64x64) -> tanh*vhat
// bp staging conflict-free: per-thread px, 8-channel gather -> 1 b128 write.
__global__ __launch_bounds__(256) void k_resh(const bf16* __restrict__ p, const bf16* __restrict__ vhat,
                                              const short* __restrict__ wabf,
                                              const float* __restrict__ ba1, const float* __restrict__ ba2,
                                              bf16* __restrict__ resh)
{
    __shared__ short aw1[64 * 64];       // A1[oc][ic]
    __shared__ short aw2[64 * 64];       // A2[oc][ic]
    __shared__ short bp[8 * 128 * 8];    // P  packed [ic>>3][px][ic&7]
    __shared__ short bs2[8 * 128 * 8];   // swish packed (same layout)
    __shared__ float b1s[64], b2s[64];
    int t = threadIdx.x;
    int b = blockIdx.y;
    int px0 = blockIdx.x * 128;

    if (t < 64) { b1s[t] = ba1[t]; b2s[t] = ba2[t]; }
    #pragma unroll
    for (int i = 0; i < 2; i++) {        // stage Wa1/Wa2 (bf16 pre-converted)
        int idx = i * 2048 + t * 8;
        *(short8v*)&aw1[idx] = *(const short8v*)&wabf[idx];
        *(short8v*)&aw2[idx] = *(const short8v*)&wabf[4096 + idx];
    }
    {
        int pxs = t & 127, chalf = (t >> 7) * 32;
        const short* pb = (const short*)p + (size_t)b * 64 * HW + px0 + pxs;
        #pragma unroll
        for (int pp = 0; pp < 4; pp++) {  // stage P: 8-channel gather -> b128 write
            int c0 = chalf + pp * 8;
            short8v pk;
            #pragma unroll
            for (int jj = 0; jj < 8; jj++) pk[jj] = pb[(size_t)(c0 + jj) * HW];
            *(short8v*)&bp[((c0 >> 3) * 128 + pxs) * 8] = pk;
        }
    }
    __syncthreads();

    int wave = wuniform(t >> 6);         // = mtile (M=64 -> 4 mtiles)
    int lane = t & 63;
    int quad = lane >> 4, l16 = lane & 15;
    int k0 = wave * 16 + quad * 4;       // output-channel base for this lane's C rows

    floatx4 acc1[8] = {};
    #pragma unroll
    for (int kk = 0; kk < 2; kk++) {
        short8v af = *(const short8v*)&aw1[(wave * 16 + l16) * 64 + kk * 32 + quad * 8];
        #pragma unroll
        for (int nt = 0; nt < 8; nt++) {
            short8v bf = *(const short8v*)&bp[((kk * 4 + quad) * 128 + nt * 16 + l16) * 8];
            acc1[nt] = __builtin_amdgcn_mfma_f32_16x16x32_bf16(af, bf, acc1[nt], 0, 0, 0);
        }
    }
    #pragma unroll
    for (int nt = 0; nt < 8; nt++) {     // swish + repack C-layout -> B-frag layout
        int px = nt * 16 + l16;
        short4v pk;
        #pragma unroll
        for (int r = 0; r < 4; r++) {
            float a = acc1[nt][r] + b1s[k0 + r];
            pk[r] = f2bs(a / (1.f + __expf(-a)));
        }
        *(short4v*)&bs2[((k0 >> 3) * 128 + px) * 8 + (k0 & 7)] = pk;
    }
    __syncthreads();

    floatx4 acc2[8] = {};
    #pragma unroll
    for (int kk = 0; kk < 2; kk++) {
        short8v af = *(const short8v*)&aw2[(wave * 16 + l16) * 64 + kk * 32 + quad * 8];
        #pragma unroll
        for (int nt = 0; nt < 8; nt++) {
            short8v bf = *(const short8v*)&bs2[((kk * 4 + quad) * 128 + nt * 16 + l16) * 8];
            acc2[nt] = __builtin_amdgcn_mfma_f32_16x16x32_bf16(af, bf, acc2[nt], 0, 0, 0);
        }
    }
    #pragma unroll
    for (int nt = 0; nt < 8; nt++) {
        int px = px0 + nt * 16 + l16;
        #pragma unroll
        for (int r = 0; r < 4; r++) {
            int oc = k0 + r;
            float g = tanhf((acc2[nt][r] + b2s[oc]) * 0.25f);
            float vv = b2f(vhat[(size_t)(b * 64 + oc) * HW + px]);
            resh[(size_t)(b * 64 + oc) * HW + px] = f2b(g * vv);
        }
    }
}

// ---------------- MFMA final proj: [res_h|res_l] -> out fp32. grid (128 px-tiles, 4 b) ---
// B staging conflict-free: per-thread px, 8-channel gather -> 1 b128 write.
__global__ __launch_bounds__(256) void k_proj(const bf16* __restrict__ resh, const bf16* __restrict__ qkvg,
                                              const short* __restrict__ wpbf, const float* __restrict__ bproj,
                                              float* __restrict__ out)
{
    __shared__ short a_s[128 * 128];
    __shared__ short b_s[128 * 128];
    __shared__ float bias_s[128];
    int t = threadIdx.x;
    int b = blockIdx.y;
    int px0 = blockIdx.x * 128;
    const bf16* resl = qkvg + (size_t)(b * 256 + 192) * HW;

    if (t < 128) bias_s[t] = bproj[t];
    #pragma unroll
    for (int i = 0; i < 8; i++) {        // stage A (Wproj bf16 pre-converted)
        int idx = i * 2048 + t * 8;
        *(short8v*)&a_s[idx] = *(const short8v*)&wpbf[idx];
    }
    {
        int pxs = t & 127, half = t >> 7;
        const short* srcb = half == 0 ? ((const short*)resh + (size_t)b * 64 * HW + px0 + pxs)
                                      : ((const short*)resl + px0 + pxs);
        #pragma unroll
        for (int pp = 0; pp < 8; pp++) {  // stage B: 8-channel gather -> b128 write
            int c0 = half * 64 + pp * 8;
            short8v pk;
            #pragma unroll
            for (int jj = 0; jj < 8; jj++) pk[jj] = srcb[(size_t)(pp * 8 + jj) * HW];
            *(short8v*)&b_s[((c0 >> 3) * 128 + pxs) * 8] = pk;
        }
    }
    __syncthreads();

    int wave = wuniform(t >> 6);
    int lane = t & 63;
    int quad = lane >> 4, l16 = lane & 15;
    floatx4 acc[2][8] = {};
    #pragma unroll
    for (int kk = 0; kk < 4; kk++) {
        short8v a0 = *(const short8v*)&a_s[(wave * 32 + l16) * 128 + kk * 32 + quad * 8];
        short8v a1 = *(const short8v*)&a_s[(wave * 32 + 16 + l16) * 128 + kk * 32 + quad * 8];
        #pragma unroll
        for (int nt = 0; nt < 8; nt++) {
            short8v bv = *(const short8v*)&b_s[((kk * 4 + quad) * 128 + nt * 16 + l16) * 8];
            acc[0][nt] = __builtin_amdgcn_mfma_f32_16x16x32_bf16(a0, bv, acc[0][nt], 0, 0, 0);
            acc[1][nt] = __builtin_amdgcn_mfma_f32_16x16x32_bf16(a1, bv, acc[1][nt], 0, 0, 0);
        }
    }
    #pragma unroll
    for (int m = 0; m < 2; m++) {
        int rowb = wave * 32 + m * 16 + quad * 4;
        #pragma unroll
        for (int nt = 0; nt < 8; nt++) {
            int px = px0 + nt * 16 + l16;
            #pragma unroll
            for (int r = 0; r < 4; r++) {
                int row = rowb + r;
                out[((size_t)b * 128 + row) * HW + px] = acc[m][nt][r] + bias_s[row];
            }
        }
    }
}

extern "C" void kernel_launch(void* const* d_in, const int* in_sizes, int n_in,
                              void* d_out, int out_size, void* d_ws, size_t ws_size,
                              hipStream_t stream)
{
    (void)in_sizes; (void)n_in; (void)out_size; (void)ws_size;
    const float* x     = (const float*)d_in[0];
    const float* Wqkv  = (const float*)d_in[1];
    const float* bqkv  = (const float*)d_in[2];
    const float* Wdw   = (const float*)d_in[3];
    const float* bdw   = (const float*)d_in[4];
    const float* Wa1   = (const float*)d_in[5];
    const float* ba1   = (const float*)d_in[6];
    const float* Wa2   = (const float*)d_in[7];
    const float* ba2   = (const float*)d_in[8];
    const float* Wq    = (const float*)d_in[9];
    const float* bq    = (const float*)d_in[10];
    const float* Wkv   = (const float*)d_in[11];
    const float* bkv   = (const float*)d_in[12];
    const float* Wproj = (const float*)d_in[13];
    const float* bproj = (const float*)d_in[14];

    char* wsb = (char*)d_ws;
    float* xp   = (float*)(wsb + OFFB_XP);
    float* k2   = (float*)(wsb + OFFB_K2);
    float* v2   = (float*)(wsb + OFFB_V2);
    bf16*  qkvg = (bf16*)(wsb + OFFB_QKVG);
    bf16*  resh = (bf16*)(wsb + OFFB_RESH);
    short* wconv = (short*)(wsb + OFFB_RESH); // conv weights bf16; dead before k_resh writes
    short* wlate = (short*)(wsb + OFFB_K2);   // Wproj/Wa bf16; k2 dead after k_attn
    bf16*  p    = (bf16*)d_out;               // scratch in d_out, dead before k_proj
    bf16*  v    = (bf16*)d_out + 4194304;
    float* out  = (float*)d_out;

    k_pool<<<dim3(512), 256, 0, stream>>>(x, xp, Wqkv, Wq, wconv);
    k_kv<<<dim3(64), 256, 0, stream>>>(xp, Wkv, bkv, k2, v2);
    k_conv<<<dim3(64, 2, 4), 256, 0, stream>>>(x, wconv, bqkv, bq, qkvg);
    k_dw<<<dim3(2048), 256, 0, stream>>>(qkvg, Wdw, bdw, p, v);
    k_attn<<<dim3(64, 4, 4), 256, 0, stream>>>(qkvg, k2, v2);       // res_l in-place over qg ch
    k_wcvt<<<dim3(24), 256, 0, stream>>>(Wproj, Wa1, Wa2, wlate);
    k_resh<<<dim3(128, 4), 256, 0, stream>>>(p, v, wlate + 16384, ba1, ba2, resh);
    k_proj<<<dim3(128, 4), 256, 0, stream>>>(resh, qkvg, wlate, bproj, out);
}

// Round 8
// 207.063 us; speedup vs baseline: 1.1663x; 1.1663x over previous
//
#include <hip/hip_runtime.h>
#include <hip/hip_bf16.h>

typedef __hip_bfloat16 bf16;
typedef short short8v __attribute__((ext_vector_type(8)));
typedef short short4v __attribute__((ext_vector_type(4)));
typedef float floatx4 __attribute__((ext_vector_type(4)));

#define HW 16384

__device__ __forceinline__ float b2f(bf16 v) { return __bfloat162float(v); }
__device__ __forceinline__ bf16 f2b(float v) { return __float2bfloat16(v); }
__device__ __forceinline__ short f2bs(float v) { bf16 h = __float2bfloat16(v); return __builtin_bit_cast(short, h); }
__device__ __forceinline__ float bs2f(short s) { return b2f(__builtin_bit_cast(bf16, s)); }
__device__ __forceinline__ int wuniform(int v) { return __builtin_amdgcn_readfirstlane(v); }

// ---- ws byte offsets (total 41 MiB, proven safe) ----
// xp is 512 KB: [0, 524288). NOTHING else may live below OFFB_K2 (R6 lesson: alias -> NaN).
#define OFFB_XP    0u
#define OFFB_K2    524288u            // after k_attn: bf16 weights (Wproj@0, Wa1@16384, Wa2@20480 shorts)
#define OFFB_V2    786432u
#define OFFB_QKVG  (1u << 20)         // bf16 (b,256,HW): 0-63 q, 64-127 k, 128-191 v, 192-255 qg->res_l
#define OFFB_RESH  (33u << 20)        // bf16 (b,64,HW); first 64KB = conv weights bf16 until k_resh
// p / v-hat scratch in d_out [0,16MiB); d_out fully overwritten by k_proj.

// ---------------- 8x8 avgpool + conv-weight bf16 preconvert (blocks 0-7) ----------------
__global__ __launch_bounds__(256) void k_pool(const float* __restrict__ x, float* __restrict__ xp,
                                              const float* __restrict__ Wqkv, const float* __restrict__ Wq,
                                              short* __restrict__ wconv)
{
    int idx = blockIdx.x * 256 + threadIdx.x;
    int j = idx & 15, i = (idx >> 4) & 15, bc = idx >> 8;
    const float* src = x + (size_t)bc * HW + (i * 8) * 128 + j * 8;
    float s = 0.f;
    #pragma unroll
    for (int u = 0; u < 8; u++) {
        #pragma unroll
        for (int t = 0; t < 8; t++) s += src[u * 128 + t];
    }
    xp[bc * 256 + i * 16 + j] = s * (1.f / 64.f);

    if (blockIdx.x < 8) {               // convert 32768 conv-weight floats -> bf16 (256x128 row-major)
        int base = blockIdx.x * 4096 + threadIdx.x * 16;
        #pragma unroll
        for (int e = 0; e < 16; e += 4) {
            int k = base + e;
            const float* ws = (k < 24576) ? (Wqkv + k) : (Wq + k - 24576);
            floatx4 wv = *(const floatx4*)ws;
            short4v pk;
            pk[0] = f2bs(wv[0]); pk[1] = f2bs(wv[1]); pk[2] = f2bs(wv[2]); pk[3] = f2bs(wv[3]);
            *(short4v*)&wconv[k] = pk;
        }
    }
}

// ---------------- kv conv: xp -> k2/v2 fp32 (b,h,m,d). grid (4b x 128o) = 512 ------------
// R7 fix: old version was 64 blocks with xr[128] per thread (VGPR 136, occupancy 2.3%,
// 52 us pure latency). Now: one (b,o) per block, Wkv row in LDS, 128 independent
// coalesced loads accumulated on the fly. Partial-sum order bit-identical to before.
__global__ __launch_bounds__(256) void k_kv(const float* __restrict__ xp,
                                            const float* __restrict__ Wkv, const float* __restrict__ bkv,
                                            float* __restrict__ k2, float* __restrict__ v2)
{
    __shared__ float w_s[128];
    int o = blockIdx.x & 127, b = blockIdx.x >> 7;
    int m = threadIdx.x;
    if (m < 128) w_s[m] = Wkv[o * 128 + m];
    __syncthreads();
    const float* xb = xp + b * 32768 + m;
    float s0 = 0.f, s1 = 0.f, s2 = 0.f, s3 = 0.f;
    #pragma unroll
    for (int c = 0; c < 128; c += 4) {
        s0 += w_s[c]     * xb[(size_t)(c)     * 256];
        s1 += w_s[c + 1] * xb[(size_t)(c + 1) * 256];
        s2 += w_s[c + 2] * xb[(size_t)(c + 2) * 256];
        s3 += w_s[c + 3] * xb[(size_t)(c + 3) * 256];
    }
    float a = bkv[o] + ((s0 + s1) + (s2 + s3));
    int sb = o >> 6, r = o & 63, gh = r >> 4, dh = r & 15;
    float* dst = sb == 0 ? k2 : v2;
    dst[((b * 4 + gh) * 256 + m) * 16 + dh] = a;
}

// ------- MFMA conv1x1: x -> qkvg bf16. grid (64 px-pairs, 2 m-blocks, 4 b); 2 subtiles ---
// B staging conflict-free: thread owns one px (t&127), gathers 8 consecutive channels
// (coalesced dword loads), writes ONE contiguous ds_write_b128 into the packed slot.
__global__ __launch_bounds__(256) void k_conv(const float* __restrict__ x,
                                              const short* __restrict__ wconv,
                                              const float* __restrict__ bqkv, const float* __restrict__ bq,
                                              bf16* __restrict__ qkvg)
{
    __shared__ short a_s[128 * 128];          // A[oc][k] bf16
    __shared__ short b_s[128 * 128];          // B packed [k>>3][px][k&7] bf16
    __shared__ float bias_s[128];
    int t = threadIdx.x;
    int b = blockIdx.z, my = blockIdx.y;
    int px0b = blockIdx.x * 256;

    if (t < 128) {
        int oc = my * 128 + t;
        bias_s[t] = (oc < 192) ? bqkv[oc] : bq[oc - 192];
    }
    const short* wsrc = wconv + my * 16384;   // rows my*128..my*128+127, row-major
    #pragma unroll
    for (int i = 0; i < 8; i++) {             // stage A: bf16 copy
        int idx = i * 2048 + t * 8;
        *(short8v*)&a_s[idx] = *(const short8v*)&wsrc[idx];
    }

    int wave = wuniform(t >> 6);
    int lane = t & 63;
    int quad = lane >> 4, l16 = lane & 15;
    int pxs = t & 127, chalf = (t >> 7) * 64;

    #pragma unroll 1
    for (int sub = 0; sub < 2; sub++) {
        int px0 = px0b + sub * 128;
        const float* xb = x + (size_t)b * 128 * HW + px0 + pxs;
        #pragma unroll
        for (int p = 0; p < 8; p++) {         // stage B: 8 coalesced loads -> 1 b128 write
            int c0 = chalf + p * 8;
            float xv[8];
            #pragma unroll
            for (int jj = 0; jj < 8; jj++) xv[jj] = xb[(size_t)(c0 + jj) * HW];
            short8v pk;
            #pragma unroll
            for (int jj = 0; jj < 8; jj++) pk[jj] = f2bs(xv[jj]);
            *(short8v*)&b_s[((c0 >> 3) * 128 + pxs) * 8] = pk;
        }
        __syncthreads();

        floatx4 acc[2][8] = {};
        #pragma unroll
        for (int kk = 0; kk < 4; kk++) {
            short8v a0 = *(const short8v*)&a_s[(wave * 32 + l16) * 128 + kk * 32 + quad * 8];
            short8v a1 = *(const short8v*)&a_s[(wave * 32 + 16 + l16) * 128 + kk * 32 + quad * 8];
            #pragma unroll
            for (int nt = 0; nt < 8; nt++) {
                short8v bv = *(const short8v*)&b_s[((kk * 4 + quad) * 128 + nt * 16 + l16) * 8];
                acc[0][nt] = __builtin_amdgcn_mfma_f32_16x16x32_bf16(a0, bv, acc[0][nt], 0, 0, 0);
                acc[1][nt] = __builtin_amdgcn_mfma_f32_16x16x32_bf16(a1, bv, acc[1][nt], 0, 0, 0);
            }
        }
        #pragma unroll
        for (int m = 0; m < 2; m++) {
            int rowb = wave * 32 + m * 16 + quad * 4;
            #pragma unroll
            for (int nt = 0; nt < 8; nt++) {
                int px = px0 + nt * 16 + l16;
                #pragma unroll
                for (int r = 0; r < 4; r++) {
                    int row = rowb + r;
                    float val = acc[m][nt][r] + bias_s[row];
                    qkvg[((size_t)b * 256 + my * 128 + row) * HW + px] = f2b(val);
                }
            }
        }
        __syncthreads();                      // MFMA reads done before next-sub B restage
    }
}

// ---------------- depthwise 3x3 + q*k, vectorized: 8 px/thread. grid 2048 ----------------
__global__ __launch_bounds__(256) void k_dw(const bf16* __restrict__ qkvg,
                                            const float* __restrict__ Wdw, const float* __restrict__ bdw,
                                            bf16* __restrict__ p, bf16* __restrict__ v)
{
    int blk = blockIdx.x;            // 2048
    int bc = blk >> 3;               // b*64+c
    int c = bc & 63, b = bc >> 6;
    int g = (blk & 7) * 256 + threadIdx.x;   // 0..2047 pixel-groups in plane
    int i = g >> 4;                  // row
    int j0 = (g & 15) * 8;           // col start
    float acc[3][8];
    #pragma unroll
    for (int pl = 0; pl < 3; pl++) {
        float bias = bdw[pl * 64 + c];
        #pragma unroll
        for (int t2 = 0; t2 < 8; t2++) acc[pl][t2] = bias;
    }
    #pragma unroll
    for (int pl = 0; pl < 3; pl++) {
        const bf16* plane = qkvg + (size_t)(b * 256 + pl * 64 + c) * HW;
        const float* w = Wdw + (pl * 64 + c) * 9;
        #pragma unroll
        for (int dy = 0; dy < 3; dy++) {
            int ii = i + dy - 1;
            float e[10];
            if ((unsigned)ii < 128u) {
                const bf16* r = plane + ii * 128 + j0;
                short8v v8 = *(const short8v*)r;
                #pragma unroll
                for (int t2 = 0; t2 < 8; t2++) e[t2 + 1] = bs2f(v8[t2]);
                e[0] = (j0 > 0) ? b2f(r[-1]) : 0.f;
                e[9] = (j0 < 120) ? b2f(r[8]) : 0.f;
            } else {
                #pragma unroll
                for (int t2 = 0; t2 < 10; t2++) e[t2] = 0.f;
            }
            float wa = w[dy * 3], wb = w[dy * 3 + 1], wc = w[dy * 3 + 2];
            #pragma unroll
            for (int t2 = 0; t2 < 8; t2++)
                acc[pl][t2] += wa * e[t2] + wb * e[t2 + 1] + wc * e[t2 + 2];
        }
    }
    short8v pv, vv;
    #pragma unroll
    for (int t2 = 0; t2 < 8; t2++) {
        pv[t2] = f2bs(acc[0][t2] * acc[1][t2]);
        vv[t2] = f2bs(acc[2][t2]);
    }
    size_t off = (size_t)(b * 64 + c) * HW + i * 128 + j0;
    *(short8v*)(p + off) = pv;
    *(short8v*)(v + off) = vv;
}

// ---------------- MFMA low-freq attention. grid (64 px-blocks, 4 h, 4 b) ----------------
// In-register P (proven R4): key-permuted K staging aligns QK C-layout with PV B-frag
// slots; P stays in VGPRs (clamp -> exp2 -> f2bs -> PV MFMA). LDS 40 KiB, 4 blocks/CU.
__global__ __launch_bounds__(256, 4) void k_attn(bf16* __restrict__ qkvg, const float* __restrict__ k2,
                                                 const float* __restrict__ v2)
{
    __shared__ short kt[16 * 64 * 8];   // 16 KiB: K A-frags (key-permuted), k=16..31 zero
    __shared__ short vt[8 * 64 * 8];    // 8 KiB: V frags (A-role: V^T)
    __shared__ short un[16 * 64 * 8];   // 16 KiB: Q B-frag staging
    int t = threadIdx.x;
    int h = blockIdx.y, b = blockIdx.z;
    int px0b = blockIdx.x * 256;
    const float* K = k2 + (size_t)(b * 4 + h) * 4096;
    const float* V = v2 + (size_t)(b * 4 + h) * 4096;
    bf16* Qbase = qkvg + (size_t)(b * 256 + 192 + h * 16) * HW + px0b;

    {
        int mb = t >> 5, kl = t & 31, q = kl >> 3, s = kl & 7;
        int tile = 2 * mb + (s >> 2), row = q * 4 + (s & 3);
        float4 k0 = *(const float4*)(K + t * 16);
        float4 k1 = *(const float4*)(K + t * 16 + 4);
        float4 kx2 = *(const float4*)(K + t * 16 + 8);
        float4 k3 = *(const float4*)(K + t * 16 + 12);
        short8v lo, hi, zz = {};
        lo[0] = f2bs(k0.x); lo[1] = f2bs(k0.y); lo[2] = f2bs(k0.z); lo[3] = f2bs(k0.w);
        lo[4] = f2bs(k1.x); lo[5] = f2bs(k1.y); lo[6] = f2bs(k1.z); lo[7] = f2bs(k1.w);
        hi[0] = f2bs(kx2.x); hi[1] = f2bs(kx2.y); hi[2] = f2bs(kx2.z); hi[3] = f2bs(kx2.w);
        hi[4] = f2bs(k3.x); hi[5] = f2bs(k3.y); hi[6] = f2bs(k3.z); hi[7] = f2bs(k3.w);
        *(short8v*)&kt[(tile * 64 + row) * 8] = lo;
        *(short8v*)&kt[(tile * 64 + 16 + row) * 8] = hi;
        *(short8v*)&kt[(tile * 64 + 32 + row) * 8] = zz;
        *(short8v*)&kt[(tile * 64 + 48 + row) * 8] = zz;
    }
    #pragma unroll
    for (int u = 0; u < 2; u++) {
        int f = t * 2 + u;
        int mb = f >> 6, lane = f & 63, quad = lane >> 4, d = lane & 15;
        short8v pk;
        #pragma unroll
        for (int i = 0; i < 8; i++) pk[i] = f2bs(V[(mb * 32 + quad * 8 + i) * 16 + d]);
        *(short8v*)&vt[f * 8] = pk;
    }
    #pragma unroll
    for (int u = 0; u < 4; u++) {
        int f = t * 4 + u;
        int pxt = f >> 6, lane = f & 63, quad = lane >> 4, l16 = lane & 15;
        int px = pxt * 16 + l16;
        short8v pk = {};
        if (quad < 2) {
            #pragma unroll
            for (int i = 0; i < 8; i++)   // 0.25 (= dh^-0.5) * log2(e) folded in
                pk[i] = f2bs(b2f(Qbase[(size_t)(quad * 8 + i) * HW + px]) * 0.36067376022224085f);
        }
        *(short8v*)&un[f * 8] = pk;
    }
    __syncthreads();

    int wave = wuniform(t >> 6);
    int lane = t & 63;
    int quad = lane >> 4, l16 = lane & 15;
    short8v qf[4];
    #pragma unroll
    for (int u = 0; u < 4; u++)
        qf[u] = *(const short8v*)&un[((wave * 4 + u) * 64 + lane) * 8];

    #pragma unroll
    for (int u = 0; u < 4; u++) {
        int pxt = wave * 4 + u;
        floatx4 denv = {};
        floatx4 oa = {};
        #pragma unroll
        for (int mb = 0; mb < 8; mb++) {
            short8v kfE = *(const short8v*)&kt[((2 * mb) * 64 + lane) * 8];
            short8v kfO = *(const short8v*)&kt[((2 * mb + 1) * 64 + lane) * 8];
            floatx4 scE = __builtin_amdgcn_mfma_f32_16x16x32_bf16(kfE, qf[u], (floatx4){0.f, 0.f, 0.f, 0.f}, 0, 0, 0);
            floatx4 scO = __builtin_amdgcn_mfma_f32_16x16x32_bf16(kfO, qf[u], (floatx4){0.f, 0.f, 0.f, 0.f}, 0, 0, 0);
            floatx4 peE, peO;
            #pragma unroll
            for (int r = 0; r < 4; r++) {
                peE[r] = exp2f(fminf(scE[r], 86.f));
                peO[r] = exp2f(fminf(scO[r], 86.f));
            }
            denv += peE;
            denv += peO;
            short8v pa;
            pa[0] = f2bs(peE[0]); pa[1] = f2bs(peE[1]); pa[2] = f2bs(peE[2]); pa[3] = f2bs(peE[3]);
            pa[4] = f2bs(peO[0]); pa[5] = f2bs(peO[1]); pa[6] = f2bs(peO[2]); pa[7] = f2bs(peO[3]);
            short8v vf = *(const short8v*)&vt[(mb * 64 + lane) * 8];
            oa = __builtin_amdgcn_mfma_f32_16x16x32_bf16(vf, pa, oa, 0, 0, 0);
        }
        float den = (denv[0] + denv[1]) + (denv[2] + denv[3]);
        den += __shfl_xor(den, 16, 64);
        den += __shfl_xor(den, 32, 64);
        float rden = 1.f / den;
        #pragma unroll
        for (int r = 0; r < 4; r++)
            Qbase[(size_t)(quad * 4 + r) * HW + pxt * 16 + l16] = f2b(oa[r] * rden);
    }
}

// ---------------- late-weight bf16 preconvert: Wproj/Wa1/Wa2 -> k2 region (dead) ---------
__global__ __launch_bounds__(256) void k_wcvt(const float* __restrict__ Wproj,
                                              const float* __restrict__ Wa1, const float* __restrict__ Wa2,
                                              short* __restrict__ wdst)
{
    int idx = blockIdx.x * 1024 + threadIdx.x * 4;   // 24 blocks -> 24576 floats
    const float* src;
    if (idx < 16384)      src = Wproj + idx;
    else if (idx < 20480) src = Wa1 + (idx - 16384);
    else                  src = Wa2 + (idx - 20480);
    floatx4 wv = *(const floatx4*)src;
    short4v pk;
    pk[0] = f2bs(wv[0]); pk[1] = f2bs(wv[1]); pk[2] = f2bs(wv[2]); pk[3] = f2bs(wv[3]);
    *(short4v*)&wdst[idx] = pk;
}

// ---------------- MFMA high-freq gate: p,v-hat -> res_h. grid (128 px-tiles, 4 b) --------
// GEMM1 (Wa1 64x64 · P) -> swish -> repack -> GEMM2 (Wa2 64x64) -> tanh*vhat
// bp staging conflict-free: per-thread px, 8-channel gather -> 1 b128 write.
__global__ __launch_bounds__(256) void k_resh(const bf16* __restrict__ p, const bf16* __restrict__ vhat,
                                              const short* __restrict__ wabf,
                                              const float* __restrict__ ba1, const float* __restrict__ ba2,
                                              bf16* __restrict__ resh)
{
    __shared__ short aw1[64 * 64];       // A1[oc][ic]
    __shared__ short aw2[64 * 64];       // A2[oc][ic]
    __shared__ short bp[8 * 128 * 8];    // P  packed [ic>>3][px][ic&7]
    __shared__ short bs2[8 * 128 * 8];   // swish packed (same layout)
    __shared__ float b1s[64], b2s[64];
    int t = threadIdx.x;
    int b = blockIdx.y;
    int px0 = blockIdx.x * 128;

    if (t < 64) { b1s[t] = ba1[t]; b2s[t] = ba2[t]; }
    #pragma unroll
    for (int i = 0; i < 2; i++) {        // stage Wa1/Wa2 (bf16 pre-converted)
        int idx = i * 2048 + t * 8;
        *(short8v*)&aw1[idx] = *(const short8v*)&wabf[idx];
        *(short8v*)&aw2[idx] = *(const short8v*)&wabf[4096 + idx];
    }
    {
        int pxs = t & 127, chalf = (t >> 7) * 32;
        const short* pb = (const short*)p + (size_t)b * 64 * HW + px0 + pxs;
        #pragma unroll
        for (int pp = 0; pp < 4; pp++) {  // stage P: 8-channel gather -> b128 write
            int c0 = chalf + pp * 8;
            short8v pk;
            #pragma unroll
            for (int jj = 0; jj < 8; jj++) pk[jj] = pb[(size_t)(c0 + jj) * HW];
            *(short8v*)&bp[((c0 >> 3) * 128 + pxs) * 8] = pk;
        }
    }
    __syncthreads();

    int wave = wuniform(t >> 6);         // = mtile (M=64 -> 4 mtiles)
    int lane = t & 63;
    int quad = lane >> 4, l16 = lane & 15;
    int k0 = wave * 16 + quad * 4;       // output-channel base for this lane's C rows

    floatx4 acc1[8] = {};
    #pragma unroll
    for (int kk = 0; kk < 2; kk++) {
        short8v af = *(const short8v*)&aw1[(wave * 16 + l16) * 64 + kk * 32 + quad * 8];
        #pragma unroll
        for (int nt = 0; nt < 8; nt++) {
            short8v bf = *(const short8v*)&bp[((kk * 4 + quad) * 128 + nt * 16 + l16) * 8];
            acc1[nt] = __builtin_amdgcn_mfma_f32_16x16x32_bf16(af, bf, acc1[nt], 0, 0, 0);
        }
    }
    #pragma unroll
    for (int nt = 0; nt < 8; nt++) {     // swish + repack C-layout -> B-frag layout
        int px = nt * 16 + l16;
        short4v pk;
        #pragma unroll
        for (int r = 0; r < 4; r++) {
            float a = acc1[nt][r] + b1s[k0 + r];
            pk[r] = f2bs(a / (1.f + __expf(-a)));
        }
        *(short4v*)&bs2[((k0 >> 3) * 128 + px) * 8 + (k0 & 7)] = pk;
    }
    __syncthreads();

    floatx4 acc2[8] = {};
    #pragma unroll
    for (int kk = 0; kk < 2; kk++) {
        short8v af = *(const short8v*)&aw2[(wave * 16 + l16) * 64 + kk * 32 + quad * 8];
        #pragma unroll
        for (int nt = 0; nt < 8; nt++) {
            short8v bf = *(const short8v*)&bs2[((kk * 4 + quad) * 128 + nt * 16 + l16) * 8];
            acc2[nt] = __builtin_amdgcn_mfma_f32_16x16x32_bf16(af, bf, acc2[nt], 0, 0, 0);
        }
    }
    #pragma unroll
    for (int nt = 0; nt < 8; nt++) {
        int px = px0 + nt * 16 + l16;
        #pragma unroll
        for (int r = 0; r < 4; r++) {
            int oc = k0 + r;
            float g = tanhf((acc2[nt][r] + b2s[oc]) * 0.25f);
            float vv = b2f(vhat[(size_t)(b * 64 + oc) * HW + px]);
            resh[(size_t)(b * 64 + oc) * HW + px] = f2b(g * vv);
        }
    }
}

// ---------------- MFMA final proj: [res_h|res_l] -> out fp32. grid (128 px-tiles, 4 b) ---
// B staging conflict-free: per-thread px, 8-channel gather -> 1 b128 write.
__global__ __launch_bounds__(256) void k_proj(const bf16* __restrict__ resh, const bf16* __restrict__ qkvg,
                                              const short* __restrict__ wpbf, const float* __restrict__ bproj,
                                              float* __restrict__ out)
{
    __shared__ short a_s[128 * 128];
    __shared__ short b_s[128 * 128];
    __shared__ float bias_s[128];
    int t = threadIdx.x;
    int b = blockIdx.y;
    int px0 = blockIdx.x * 128;
    const bf16* resl = qkvg + (size_t)(b * 256 + 192) * HW;

    if (t < 128) bias_s[t] = bproj[t];
    #pragma unroll
    for (int i = 0; i < 8; i++) {        // stage A (Wproj bf16 pre-converted)
        int idx = i * 2048 + t * 8;
        *(short8v*)&a_s[idx] = *(const short8v*)&wpbf[idx];
    }
    {
        int pxs = t & 127, half = t >> 7;
        const short* srcb = half == 0 ? ((const short*)resh + (size_t)b * 64 * HW + px0 + pxs)
                                      : ((const short*)resl + px0 + pxs);
        #pragma unroll
        for (int pp = 0; pp < 8; pp++) {  // stage B: 8-channel gather -> b128 write
            int c0 = half * 64 + pp * 8;
            short8v pk;
            #pragma unroll
            for (int jj = 0; jj < 8; jj++) pk[jj] = srcb[(size_t)(pp * 8 + jj) * HW];
            *(short8v*)&b_s[((c0 >> 3) * 128 + pxs) * 8] = pk;
        }
    }
    __syncthreads();

    int wave = wuniform(t >> 6);
    int lane = t & 63;
    int quad = lane >> 4, l16 = lane & 15;
    floatx4 acc[2][8] = {};
    #pragma unroll
    for (int kk = 0; kk < 4; kk++) {
        short8v a0 = *(const short8v*)&a_s[(wave * 32 + l16) * 128 + kk * 32 + quad * 8];
        short8v a1 = *(const short8v*)&a_s[(wave * 32 + 16 + l16) * 128 + kk * 32 + quad * 8];
        #pragma unroll
        for (int nt = 0; nt < 8; nt++) {
            short8v bv = *(const short8v*)&b_s[((kk * 4 + quad) * 128 + nt * 16 + l16) * 8];
            acc[0][nt] = __builtin_amdgcn_mfma_f32_16x16x32_bf16(a0, bv, acc[0][nt], 0, 0, 0);
            acc[1][nt] = __builtin_amdgcn_mfma_f32_16x16x32_bf16(a1, bv, acc[1][nt], 0, 0, 0);
        }
    }
    #pragma unroll
    for (int m = 0; m < 2; m++) {
        int rowb = wave * 32 + m * 16 + quad * 4;
        #pragma unroll
        for (int nt = 0; nt < 8; nt++) {
            int px = px0 + nt * 16 + l16;
            #pragma unroll
            for (int r = 0; r < 4; r++) {
                int row = rowb + r;
                out[((size_t)b * 128 + row) * HW + px] = acc[m][nt][r] + bias_s[row];
            }
        }
    }
}

extern "C" void kernel_launch(void* const* d_in, const int* in_sizes, int n_in,
                              void* d_out, int out_size, void* d_ws, size_t ws_size,
                              hipStream_t stream)
{
    (void)in_sizes; (void)n_in; (void)out_size; (void)ws_size;
    const float* x     = (const float*)d_in[0];
    const float* Wqkv  = (const float*)d_in[1];
    const float* bqkv  = (const float*)d_in[2];
    const float* Wdw   = (const float*)d_in[3];
    const float* bdw   = (const float*)d_in[4];
    const float* Wa1   = (const float*)d_in[5];
    const float* ba1   = (const float*)d_in[6];
    const float* Wa2   = (const float*)d_in[7];
    const float* ba2   = (const float*)d_in[8];
    const float* Wq    = (const float*)d_in[9];
    const float* bq    = (const float*)d_in[10];
    const float* Wkv   = (const float*)d_in[11];
    const float* bkv   = (const float*)d_in[12];
    const float* Wproj = (const float*)d_in[13];
    const float* bproj = (const float*)d_in[14];

    char* wsb = (char*)d_ws;
    float* xp   = (float*)(wsb + OFFB_XP);
    float* k2   = (float*)(wsb + OFFB_K2);
    float* v2   = (float*)(wsb + OFFB_V2);
    bf16*  qkvg = (bf16*)(wsb + OFFB_QKVG);
    bf16*  resh = (bf16*)(wsb + OFFB_RESH);
    short* wconv = (short*)(wsb + OFFB_RESH); // conv weights bf16; dead before k_resh writes
    short* wlate = (short*)(wsb + OFFB_K2);   // Wproj/Wa bf16; k2 dead after k_attn
    bf16*  p    = (bf16*)d_out;               // scratch in d_out, dead before k_proj
    bf16*  v    = (bf16*)d_out + 4194304;
    float* out  = (float*)d_out;

    k_pool<<<dim3(512), 256, 0, stream>>>(x, xp, Wqkv, Wq, wconv);
    k_kv<<<dim3(512), 256, 0, stream>>>(xp, Wkv, bkv, k2, v2);
    k_conv<<<dim3(64, 2, 4), 256, 0, stream>>>(x, wconv, bqkv, bq, qkvg);
    k_dw<<<dim3(2048), 256, 0, stream>>>(qkvg, Wdw, bdw, p, v);
    k_attn<<<dim3(64, 4, 4), 256, 0, stream>>>(qkvg, k2, v2);       // res_l in-place over qg ch
    k_wcvt<<<dim3(24), 256, 0, stream>>>(Wproj, Wa1, Wa2, wlate);
    k_resh<<<dim3(128, 4), 256, 0, stream>>>(p, v, wlate + 16384, ba1, ba2, resh);
    k_proj<<<dim3(128, 4), 256, 0, stream>>>(resh, qkvg, wlate, bproj, out);
}

// Round 10
// 201.832 us; speedup vs baseline: 1.1965x; 1.0259x over previous
//
#include <hip/hip_runtime.h>
#include <hip/hip_bf16.h>

typedef __hip_bfloat16 bf16;
typedef short short8v __attribute__((ext_vector_type(8)));
typedef short short4v __attribute__((ext_vector_type(4)));
typedef float floatx4 __attribute__((ext_vector_type(4)));

#define HW 16384

__device__ __forceinline__ float b2f(bf16 v) { return __bfloat162float(v); }
__device__ __forceinline__ bf16 f2b(float v) { return __float2bfloat16(v); }
__device__ __forceinline__ short f2bs(float v) { bf16 h = __float2bfloat16(v); return __builtin_bit_cast(short, h); }
__device__ __forceinline__ float bs2f(short s) { return b2f(__builtin_bit_cast(bf16, s)); }
__device__ __forceinline__ int wuniform(int v) { return __builtin_amdgcn_readfirstlane(v); }

// ---- ws byte offsets (total 41 MiB, proven safe) ----
// xp is 512 KB: [0, 524288). NOTHING else may live below OFFB_K2 (R6 lesson: alias -> NaN).
#define OFFB_XP    0u
#define OFFB_K2    524288u            // after k_attn: bf16 weights (Wproj@0, Wa1@16384, Wa2@20480 shorts)
#define OFFB_V2    786432u
#define OFFB_QKVG  (1u << 20)         // bf16 (b,256,HW): 0-63 q, 64-127 k, 128-191 v, 192-255 qg->res_l
#define OFFB_RESH  (33u << 20)        // bf16 (b,64,HW); first 64KB = conv weights bf16 until k_resh
// p / v-hat scratch in d_out [0,16MiB); d_out fully overwritten by k_proj.

// ---------------- 8x8 avgpool + conv-weight bf16 preconvert (blocks 0-7) ----------------
__global__ __launch_bounds__(256) void k_pool(const float* __restrict__ x, float* __restrict__ xp,
                                              const float* __restrict__ Wqkv, const float* __restrict__ Wq,
                                              short* __restrict__ wconv)
{
    int idx = blockIdx.x * 256 + threadIdx.x;
    int j = idx & 15, i = (idx >> 4) & 15, bc = idx >> 8;
    const float* src = x + (size_t)bc * HW + (i * 8) * 128 + j * 8;
    float s = 0.f;
    #pragma unroll
    for (int u = 0; u < 8; u++) {
        #pragma unroll
        for (int t = 0; t < 8; t++) s += src[u * 128 + t];
    }
    xp[bc * 256 + i * 16 + j] = s * (1.f / 64.f);

    if (blockIdx.x < 8) {               // convert 32768 conv-weight floats -> bf16 (256x128 row-major)
        int base = blockIdx.x * 4096 + threadIdx.x * 16;
        #pragma unroll
        for (int e = 0; e < 16; e += 4) {
            int k = base + e;
            const float* ws = (k < 24576) ? (Wqkv + k) : (Wq + k - 24576);
            floatx4 wv = *(const floatx4*)ws;
            short4v pk;
            pk[0] = f2bs(wv[0]); pk[1] = f2bs(wv[1]); pk[2] = f2bs(wv[2]); pk[3] = f2bs(wv[3]);
            *(short4v*)&wconv[k] = pk;
        }
    }
}

// ---------------- kv conv: xp -> k2/v2 fp32 (b,h,m,d). grid (4b x 128o) = 512 ------------
// R7 fix: one (b,o) per block, Wkv row in LDS, 128 independent coalesced loads.
// Partial-sum order bit-identical to original.
__global__ __launch_bounds__(256) void k_kv(const float* __restrict__ xp,
                                            const float* __restrict__ Wkv, const float* __restrict__ bkv,
                                            float* __restrict__ k2, float* __restrict__ v2)
{
    __shared__ float w_s[128];
    int o = blockIdx.x & 127, b = blockIdx.x >> 7;
    int m = threadIdx.x;
    if (m < 128) w_s[m] = Wkv[o * 128 + m];
    __syncthreads();
    const float* xb = xp + b * 32768 + m;
    float s0 = 0.f, s1 = 0.f, s2 = 0.f, s3 = 0.f;
    #pragma unroll
    for (int c = 0; c < 128; c += 4) {
        s0 += w_s[c]     * xb[(size_t)(c)     * 256];
        s1 += w_s[c + 1] * xb[(size_t)(c + 1) * 256];
        s2 += w_s[c + 2] * xb[(size_t)(c + 2) * 256];
        s3 += w_s[c + 3] * xb[(size_t)(c + 3) * 256];
    }
    float a = bkv[o] + ((s0 + s1) + (s2 + s3));
    int sb = o >> 6, r = o & 63, gh = r >> 4, dh = r & 15;
    float* dst = sb == 0 ? k2 : v2;
    dst[((b * 4 + gh) * 256 + m) * 16 + dh] = a;
}

// ------- MFMA conv1x1: x -> qkvg bf16. grid (64 px-pairs, 2 m-blocks, 4 b); 2 subtiles ---
// B staging conflict-free: thread owns one px (t&127), gathers 8 consecutive channels
// (coalesced dword loads), writes ONE contiguous ds_write_b128 into the packed slot.
__global__ __launch_bounds__(256) void k_conv(const float* __restrict__ x,
                                              const short* __restrict__ wconv,
                                              const float* __restrict__ bqkv, const float* __restrict__ bq,
                                              bf16* __restrict__ qkvg)
{
    __shared__ short a_s[128 * 128];          // A[oc][k] bf16
    __shared__ short b_s[128 * 128];          // B packed [k>>3][px][k&7] bf16
    __shared__ float bias_s[128];
    int t = threadIdx.x;
    int b = blockIdx.z, my = blockIdx.y;
    int px0b = blockIdx.x * 256;

    if (t < 128) {
        int oc = my * 128 + t;
        bias_s[t] = (oc < 192) ? bqkv[oc] : bq[oc - 192];
    }
    const short* wsrc = wconv + my * 16384;   // rows my*128..my*128+127, row-major
    #pragma unroll
    for (int i = 0; i < 8; i++) {             // stage A: bf16 copy
        int idx = i * 2048 + t * 8;
        *(short8v*)&a_s[idx] = *(const short8v*)&wsrc[idx];
    }

    int wave = wuniform(t >> 6);
    int lane = t & 63;
    int quad = lane >> 4, l16 = lane & 15;
    int pxs = t & 127, chalf = (t >> 7) * 64;

    #pragma unroll 1
    for (int sub = 0; sub < 2; sub++) {
        int px0 = px0b + sub * 128;
        const float* xb = x + (size_t)b * 128 * HW + px0 + pxs;
        #pragma unroll
        for (int p = 0; p < 8; p++) {         // stage B: 8 coalesced loads -> 1 b128 write
            int c0 = chalf + p * 8;
            float xv[8];
            #pragma unroll
            for (int jj = 0; jj < 8; jj++) xv[jj] = xb[(size_t)(c0 + jj) * HW];
            short8v pk;
            #pragma unroll
            for (int jj = 0; jj < 8; jj++) pk[jj] = f2bs(xv[jj]);
            *(short8v*)&b_s[((c0 >> 3) * 128 + pxs) * 8] = pk;
        }
        __syncthreads();

        floatx4 acc[2][8] = {};
        #pragma unroll
        for (int kk = 0; kk < 4; kk++) {
            short8v a0 = *(const short8v*)&a_s[(wave * 32 + l16) * 128 + kk * 32 + quad * 8];
            short8v a1 = *(const short8v*)&a_s[(wave * 32 + 16 + l16) * 128 + kk * 32 + quad * 8];
            #pragma unroll
            for (int nt = 0; nt < 8; nt++) {
                short8v bv = *(const short8v*)&b_s[((kk * 4 + quad) * 128 + nt * 16 + l16) * 8];
                acc[0][nt] = __builtin_amdgcn_mfma_f32_16x16x32_bf16(a0, bv, acc[0][nt], 0, 0, 0);
                acc[1][nt] = __builtin_amdgcn_mfma_f32_16x16x32_bf16(a1, bv, acc[1][nt], 0, 0, 0);
            }
        }
        #pragma unroll
        for (int m = 0; m < 2; m++) {
            int rowb = wave * 32 + m * 16 + quad * 4;
            #pragma unroll
            for (int nt = 0; nt < 8; nt++) {
                int px = px0 + nt * 16 + l16;
                #pragma unroll
                for (int r = 0; r < 4; r++) {
                    int row = rowb + r;
                    float val = acc[m][nt][r] + bias_s[row];
                    qkvg[((size_t)b * 256 + my * 128 + row) * HW + px] = f2b(val);
                }
            }
        }
        __syncthreads();                      // MFMA reads done before next-sub B restage
    }
}

// ---------------- depthwise 3x3 + q*k, vectorized: 8 px/thread. grid 2048 ----------------
__global__ __launch_bounds__(256) void k_dw(const bf16* __restrict__ qkvg,
                                            const float* __restrict__ Wdw, const float* __restrict__ bdw,
                                            bf16* __restrict__ p, bf16* __restrict__ v)
{
    int blk = blockIdx.x;            // 2048
    int bc = blk >> 3;               // b*64+c
    int c = bc & 63, b = bc >> 6;
    int g = (blk & 7) * 256 + threadIdx.x;   // 0..2047 pixel-groups in plane
    int i = g >> 4;                  // row
    int j0 = (g & 15) * 8;           // col start
    float acc[3][8];
    #pragma unroll
    for (int pl = 0; pl < 3; pl++) {
        float bias = bdw[pl * 64 + c];
        #pragma unroll
        for (int t2 = 0; t2 < 8; t2++) acc[pl][t2] = bias;
    }
    #pragma unroll
    for (int pl = 0; pl < 3; pl++) {
        const bf16* plane = qkvg + (size_t)(b * 256 + pl * 64 + c) * HW;
        const float* w = Wdw + (pl * 64 + c) * 9;
        #pragma unroll
        for (int dy = 0; dy < 3; dy++) {
            int ii = i + dy - 1;
            float e[10];
            if ((unsigned)ii < 128u) {
                const bf16* r = plane + ii * 128 + j0;
                short8v v8 = *(const short8v*)r;
                #pragma unroll
                for (int t2 = 0; t2 < 8; t2++) e[t2 + 1] = bs2f(v8[t2]);
                e[0] = (j0 > 0) ? b2f(r[-1]) : 0.f;
                e[9] = (j0 < 120) ? b2f(r[8]) : 0.f;
            } else {
                #pragma unroll
                for (int t2 = 0; t2 < 10; t2++) e[t2] = 0.f;
            }
            float wa = w[dy * 3], wb = w[dy * 3 + 1], wc = w[dy * 3 + 2];
            #pragma unroll
            for (int t2 = 0; t2 < 8; t2++)
                acc[pl][t2] += wa * e[t2] + wb * e[t2 + 1] + wc * e[t2 + 2];
        }
    }
    short8v pv, vv;
    #pragma unroll
    for (int t2 = 0; t2 < 8; t2++) {
        pv[t2] = f2bs(acc[0][t2] * acc[1][t2]);
        vv[t2] = f2bs(acc[2][t2]);
    }
    size_t off = (size_t)(b * 64 + c) * HW + i * 128 + j0;
    *(short8v*)(p + off) = pv;
    *(short8v*)(v + off) = vv;
}

// ---------------- MFMA low-freq attention. grid (64 px-blocks, 4 h, 4 b), 512 thr -------
// In-register P (proven R4). R9: 8 waves/block (was 4), each wave covers 2 pxt (was 4) --
// same total work, double TLP: 4 blocks/CU x 8 waves = 32 waves/CU (chip max) to cover
// the ~65% latency stalls seen at 4 waves/SIMD. Arithmetic bit-identical.
__global__ __launch_bounds__(512, 8) void k_attn(bf16* __restrict__ qkvg, const float* __restrict__ k2,
                                                 const float* __restrict__ v2)
{
    __shared__ short kt[16 * 64 * 8];   // 16 KiB: K A-frags (key-permuted), k=16..31 zero
    __shared__ short vt[8 * 64 * 8];    // 8 KiB: V frags (A-role: V^T)
    __shared__ short un[16 * 64 * 8];   // 16 KiB: Q B-frag staging
    int t = threadIdx.x;
    int h = blockIdx.y, b = blockIdx.z;
    int px0b = blockIdx.x * 256;
    const float* K = k2 + (size_t)(b * 4 + h) * 4096;
    const float* V = v2 + (size_t)(b * 4 + h) * 4096;
    bf16* Qbase = qkvg + (size_t)(b * 256 + 192 + h * 16) * HW + px0b;

    if (t < 256) {
        int mb = t >> 5, kl = t & 31, q = kl >> 3, s = kl & 7;
        int tile = 2 * mb + (s >> 2), row = q * 4 + (s & 3);
        float4 k0 = *(const float4*)(K + t * 16);
        float4 k1 = *(const float4*)(K + t * 16 + 4);
        float4 kx2 = *(const float4*)(K + t * 16 + 8);
        float4 k3 = *(const float4*)(K + t * 16 + 12);
        short8v lo, hi, zz = {};
        lo[0] = f2bs(k0.x); lo[1] = f2bs(k0.y); lo[2] = f2bs(k0.z); lo[3] = f2bs(k0.w);
        lo[4] = f2bs(k1.x); lo[5] = f2bs(k1.y); lo[6] = f2bs(k1.z); lo[7] = f2bs(k1.w);
        hi[0] = f2bs(kx2.x); hi[1] = f2bs(kx2.y); hi[2] = f2bs(kx2.z); hi[3] = f2bs(kx2.w);
        hi[4] = f2bs(k3.x); hi[5] = f2bs(k3.y); hi[6] = f2bs(k3.z); hi[7] = f2bs(k3.w);
        *(short8v*)&kt[(tile * 64 + row) * 8] = lo;
        *(short8v*)&kt[(tile * 64 + 16 + row) * 8] = hi;
        *(short8v*)&kt[(tile * 64 + 32 + row) * 8] = zz;
        *(short8v*)&kt[(tile * 64 + 48 + row) * 8] = zz;
    }
    {
        int f = t;                          // 512 V frags, one per thread
        int mb = f >> 6, lane = f & 63, quad = lane >> 4, d = lane & 15;
        short8v pk;
        #pragma unroll
        for (int i = 0; i < 8; i++) pk[i] = f2bs(V[(mb * 32 + quad * 8 + i) * 16 + d]);
        *(short8v*)&vt[f * 8] = pk;
    }
    #pragma unroll
    for (int u = 0; u < 2; u++) {           // 1024 Q frags, two per thread
        int f = t * 2 + u;
        int pxt = f >> 6, lane = f & 63, quad = lane >> 4, l16 = lane & 15;
        int px = pxt * 16 + l16;
        short8v pk = {};
        if (quad < 2) {
            #pragma unroll
            for (int i = 0; i < 8; i++)   // 0.25 (= dh^-0.5) * log2(e) folded in
                pk[i] = f2bs(b2f(Qbase[(size_t)(quad * 8 + i) * HW + px]) * 0.36067376022224085f);
        }
        *(short8v*)&un[f * 8] = pk;
    }
    __syncthreads();

    int wave = wuniform(t >> 6);            // 0..7
    int lane = t & 63;
    int quad = lane >> 4, l16 = lane & 15;
    short8v qf[2];
    #pragma unroll
    for (int u = 0; u < 2; u++)
        qf[u] = *(const short8v*)&un[((wave * 2 + u) * 64 + lane) * 8];

    #pragma unroll
    for (int u = 0; u < 2; u++) {
        int pxt = wave * 2 + u;
        floatx4 denv = {};
        floatx4 oa = {};
        #pragma unroll
        for (int mb = 0; mb < 8; mb++) {
            short8v kfE = *(const short8v*)&kt[((2 * mb) * 64 + lane) * 8];
            short8v kfO = *(const short8v*)&kt[((2 * mb + 1) * 64 + lane) * 8];
            floatx4 scE = __builtin_amdgcn_mfma_f32_16x16x32_bf16(kfE, qf[u], (floatx4){0.f, 0.f, 0.f, 0.f}, 0, 0, 0);
            floatx4 scO = __builtin_amdgcn_mfma_f32_16x16x32_bf16(kfO, qf[u], (floatx4){0.f, 0.f, 0.f, 0.f}, 0, 0, 0);
            floatx4 peE, peO;
            #pragma unroll
            for (int r = 0; r < 4; r++) {
                peE[r] = exp2f(fminf(scE[r], 86.f));
                peO[r] = exp2f(fminf(scO[r], 86.f));
            }
            denv += peE;
            denv += peO;
            short8v pa;
            pa[0] = f2bs(peE[0]); pa[1] = f2bs(peE[1]); pa[2] = f2bs(peE[2]); pa[3] = f2bs(peE[3]);
            pa[4] = f2bs(peO[0]); pa[5] = f2bs(peO[1]); pa[6] = f2bs(peO[2]); pa[7] = f2bs(peO[3]);
            short8v vf = *(const short8v*)&vt[(mb * 64 + lane) * 8];
            oa = __builtin_amdgcn_mfma_f32_16x16x32_bf16(vf, pa, oa, 0, 0, 0);
        }
        float den = (denv[0] + denv[1]) + (denv[2] + denv[3]);
        den += __shfl_xor(den, 16, 64);
        den += __shfl_xor(den, 32, 64);
        float rden = 1.f / den;
        #pragma unroll
        for (int r = 0; r < 4; r++)
            Qbase[(size_t)(quad * 4 + r) * HW + pxt * 16 + l16] = f2b(oa[r] * rden);
    }
}

// ---------------- late-weight bf16 preconvert: Wproj/Wa1/Wa2 -> k2 region (dead) ---------
__global__ __launch_bounds__(256) void k_wcvt(const float* __restrict__ Wproj,
                                              const float* __restrict__ Wa1, const float* __restrict__ Wa2,
                                              short* __restrict__ wdst)
{
    int idx = blockIdx.x * 1024 + threadIdx.x * 4;   // 24 blocks -> 24576 floats
    const float* src;
    if (idx < 16384)      src = Wproj + idx;
    else if (idx < 20480) src = Wa1 + (idx - 16384);
    else                  src = Wa2 + (idx - 20480);
    floatx4 wv = *(const floatx4*)src;
    short4v pk;
    pk[0] = f2bs(wv[0]); pk[1] = f2bs(wv[1]); pk[2] = f2bs(wv[2]); pk[3] = f2bs(wv[3]);
    *(short4v*)&wdst[idx] = pk;
}

// ---------------- MFMA high-freq gate: p,v-hat -> res_h. grid (128 px-tiles, 4 b) --------
// GEMM1 (Wa1 64x64 · P) -> swish -> repack -> GEMM2 (Wa2 64x64) -> tanh*vhat
// bp staging conflict-free: per-thread px, 8-channel gather -> 1 b128 write.
__global__ __launch_bounds__(256) void k_resh(const bf16* __restrict__ p, const bf16* __restrict__ vhat,
                                              const short* __restrict__ wabf,
                                              const float* __restrict__ ba1, const float* __restrict__ ba2,
                                              bf16* __restrict__ resh)
{
    __shared__ short aw1[64 * 64];       // A1[oc][ic]
    __shared__ short aw2[64 * 64];       // A2[oc][ic]
    __shared__ short bp[8 * 128 * 8];    // P  packed [ic>>3][px][ic&7]
    __shared__ short bs2[8 * 128 * 8];   // swish packed (same layout)
    __shared__ float b1s[64], b2s[64];
    int t = threadIdx.x;
    int b = blockIdx.y;
    int px0 = blockIdx.x * 128;

    if (t < 64) { b1s[t] = ba1[t]; b2s[t] = ba2[t]; }
    #pragma unroll
    for (int i = 0; i < 2; i++) {        // stage Wa1/Wa2 (bf16 pre-converted)
        int idx = i * 2048 + t * 8;
        *(short8v*)&aw1[idx] = *(const short8v*)&wabf[idx];
        *(short8v*)&aw2[idx] = *(const short8v*)&wabf[4096 + idx];
    }
    {
        int pxs = t & 127, chalf = (t >> 7) * 32;
        const short* pb = (const short*)p + (size_t)b * 64 * HW + px0 + pxs;
        #pragma unroll
        for (int pp = 0; pp < 4; pp++) {  // stage P: 8-channel gather -> b128 write
            int c0 = chalf + pp * 8;
            short8v pk;
            #pragma unroll
            for (int jj = 0; jj < 8; jj++) pk[jj] = pb[(size_t)(c0 + jj) * HW];
            *(short8v*)&bp[((c0 >> 3) * 128 + pxs) * 8] = pk;
        }
    }
    __syncthreads();

    int wave = wuniform(t >> 6);         // = mtile (M=64 -> 4 mtiles)
    int lane = t & 63;
    int quad = lane >> 4, l16 = lane & 15;
    int k0 = wave * 16 + quad * 4;       // output-channel base for this lane's C rows

    floatx4 acc1[8] = {};
    #pragma unroll
    for (int kk = 0; kk < 2; kk++) {
        short8v af = *(const short8v*)&aw1[(wave * 16 + l16) * 64 + kk * 32 + quad * 8];
        #pragma unroll
        for (int nt = 0; nt < 8; nt++) {
            short8v bf = *(const short8v*)&bp[((kk * 4 + quad) * 128 + nt * 16 + l16) * 8];
            acc1[nt] = __builtin_amdgcn_mfma_f32_16x16x32_bf16(af, bf, acc1[nt], 0, 0, 0);
        }
    }
    #pragma unroll
    for (int nt = 0; nt < 8; nt++) {     // swish + repack C-layout -> B-frag layout
        int px = nt * 16 + l16;
        short4v pk;
        #pragma unroll
        for (int r = 0; r < 4; r++) {
            float a = acc1[nt][r] + b1s[k0 + r];
            pk[r] = f2bs(a / (1.f + __expf(-a)));
        }
        *(short4v*)&bs2[((k0 >> 3) * 128 + px) * 8 + (k0 & 7)] = pk;
    }
    __syncthreads();

    floatx4 acc2[8] = {};
    #pragma unroll
    for (int kk = 0; kk < 2; kk++) {
        short8v af = *(const short8v*)&aw2[(wave * 16 + l16) * 64 + kk * 32 + quad * 8];
        #pragma unroll
        for (int nt = 0; nt < 8; nt++) {
            short8v bf = *(const short8v*)&bs2[((kk * 4 + quad) * 128 + nt * 16 + l16) * 8];
            acc2[nt] = __builtin_amdgcn_mfma_f32_16x16x32_bf16(af, bf, acc2[nt], 0, 0, 0);
        }
    }
    #pragma unroll
    for (int nt = 0; nt < 8; nt++) {
        int px = px0 + nt * 16 + l16;
        #pragma unroll
        for (int r = 0; r < 4; r++) {
            int oc = k0 + r;
            float g = tanhf((acc2[nt][r] + b2s[oc]) * 0.25f);
            float vv = b2f(vhat[(size_t)(b * 64 + oc) * HW + px]);
            resh[(size_t)(b * 64 + oc) * HW + px] = f2b(g * vv);
        }
    }
}

// ---------------- MFMA final proj: [res_h|res_l] -> out fp32. grid (128 px-tiles, 4 b) ---
// B staging conflict-free: per-thread px, 8-channel gather -> 1 b128 write.
__global__ __launch_bounds__(256) void k_proj(const bf16* __restrict__ resh, const bf16* __restrict__ qkvg,
                                              const short* __restrict__ wpbf, const float* __restrict__ bproj,
                                              float* __restrict__ out)
{
    __shared__ short a_s[128 * 128];
    __shared__ short b_s[128 * 128];
    __shared__ float bias_s[128];
    int t = threadIdx.x;
    int b = blockIdx.y;
    int px0 = blockIdx.x * 128;
    const bf16* resl = qkvg + (size_t)(b * 256 + 192) * HW;

    if (t < 128) bias_s[t] = bproj[t];
    #pragma unroll
    for (int i = 0; i < 8; i++) {        // stage A (Wproj bf16 pre-converted)
        int idx = i * 2048 + t * 8;
        *(short8v*)&a_s[idx] = *(const short8v*)&wpbf[idx];
    }
    {
        int pxs = t & 127, half = t >> 7;
        const short* srcb = half == 0 ? ((const short*)resh + (size_t)b * 64 * HW + px0 + pxs)
                                      : ((const short*)resl + px0 + pxs);
        #pragma unroll
        for (int pp = 0; pp < 8; pp++) {  // stage B: 8-channel gather -> b128 write
            int c0 = half * 64 + pp * 8;
            short8v pk;
            #pragma unroll
            for (int jj = 0; jj < 8; jj++) pk[jj] = srcb[(size_t)(pp * 8 + jj) * HW];
            *(short8v*)&b_s[((c0 >> 3) * 128 + pxs) * 8] = pk;
        }
    }
    __syncthreads();

    int wave = wuniform(t >> 6);
    int lane = t & 63;
    int quad = lane >> 4, l16 = lane & 15;
    floatx4 acc[2][8] = {};
    #pragma unroll
    for (int kk = 0; kk < 4; kk++) {
        short8v a0 = *(const short8v*)&a_s[(wave * 32 + l16) * 128 + kk * 32 + quad * 8];
        short8v a1 = *(const short8v*)&a_s[(wave * 32 + 16 + l16) * 128 + kk * 32 + quad * 8];
        #pragma unroll
        for (int nt = 0; nt < 8; nt++) {
            short8v bv = *(const short8v*)&b_s[((kk * 4 + quad) * 128 + nt * 16 + l16) * 8];
            acc[0][nt] = __builtin_amdgcn_mfma_f32_16x16x32_bf16(a0, bv, acc[0][nt], 0, 0, 0);
            acc[1][nt] = __builtin_amdgcn_mfma_f32_16x16x32_bf16(a1, bv, acc[1][nt], 0, 0, 0);
        }
    }
    #pragma unroll
    for (int m = 0; m < 2; m++) {
        int rowb = wave * 32 + m * 16 + quad * 4;
        #pragma unroll
        for (int nt = 0; nt < 8; nt++) {
            int px = px0 + nt * 16 + l16;
            #pragma unroll
            for (int r = 0; r < 4; r++) {
                int row = rowb + r;
                out[((size_t)b * 128 + row) * HW + px] = acc[m][nt][r] + bias_s[row];
            }
        }
    }
}

extern "C" void kernel_launch(void* const* d_in, const int* in_sizes, int n_in,
                              void* d_out, int out_size, void* d_ws, size_t ws_size,
                              hipStream_t stream)
{
    (void)in_sizes; (void)n_in; (void)out_size; (void)ws_size;
    const float* x     = (const float*)d_in[0];
    const float* Wqkv  = (const float*)d_in[1];
    const float* bqkv  = (const float*)d_in[2];
    const float* Wdw   = (const float*)d_in[3];
    const float* bdw   = (const float*)d_in[4];
    const float* Wa1   = (const float*)d_in[5];
    const float* ba1   = (const float*)d_in[6];
    const float* Wa2   = (const float*)d_in[7];
    const float* ba2   = (const float*)d_in[8];
    const float* Wq    = (const float*)d_in[9];
    const float* bq    = (const float*)d_in[10];
    const float* Wkv   = (const float*)d_in[11];
    const float* bkv   = (const float*)d_in[12];
    const float* Wproj = (const float*)d_in[13];
    const float* bproj = (const float*)d_in[14];

    char* wsb = (char*)d_ws;
    float* xp   = (float*)(wsb + OFFB_XP);
    float* k2   = (float*)(wsb + OFFB_K2);
    float* v2   = (float*)(wsb + OFFB_V2);
    bf16*  qkvg = (bf16*)(wsb + OFFB_QKVG);
    bf16*  resh = (bf16*)(wsb + OFFB_RESH);
    short* wconv = (short*)(wsb + OFFB_RESH); // conv weights bf16; dead before k_resh writes
    short* wlate = (short*)(wsb + OFFB_K2);   // Wproj/Wa bf16; k2 dead after k_attn
    bf16*  p    = (bf16*)d_out;               // scratch in d_out, dead before k_proj
    bf16*  v    = (bf16*)d_out + 4194304;
    float* out  = (float*)d_out;

    k_pool<<<dim3(512), 256, 0, stream>>>(x, xp, Wqkv, Wq, wconv);
    k_kv<<<dim3(512), 256, 0, stream>>>(xp, Wkv, bkv, k2, v2);
    k_conv<<<dim3(64, 2, 4), 256, 0, stream>>>(x, wconv, bqkv, bq, qkvg);
    k_dw<<<dim3(2048), 256, 0, stream>>>(qkvg, Wdw, bdw, p, v);
    k_attn<<<dim3(64, 4, 4), 512, 0, stream>>>(qkvg, k2, v2);       // res_l in-place over qg ch
    k_wcvt<<<dim3(24), 256, 0, stream>>>(Wproj, Wa1, Wa2, wlate);
    k_resh<<<dim3(128, 4), 256, 0, stream>>>(p, v, wlate + 16384, ba1, ba2, resh);
    k_proj<<<dim3(128, 4), 256, 0, stream>>>(resh, qkvg, wlate, bproj, out);
}

// Round 11
// 200.294 us; speedup vs baseline: 1.2057x; 1.0077x over previous
//
#include <hip/hip_runtime.h>
#include <hip/hip_bf16.h>

typedef __hip_bfloat16 bf16;
typedef short short8v __attribute__((ext_vector_type(8)));
typedef short short4v __attribute__((ext_vector_type(4)));
typedef float floatx4 __attribute__((ext_vector_type(4)));

#define HW 16384

__device__ __forceinline__ float b2f(bf16 v) { return __bfloat162float(v); }
__device__ __forceinline__ bf16 f2b(float v) { return __float2bfloat16(v); }
__device__ __forceinline__ short f2bs(float v) { bf16 h = __float2bfloat16(v); return __builtin_bit_cast(short, h); }
__device__ __forceinline__ float bs2f(short s) { return b2f(__builtin_bit_cast(bf16, s)); }
__device__ __forceinline__ int wuniform(int v) { return __builtin_amdgcn_readfirstlane(v); }

// ---- ws byte offsets (total 41 MiB, proven safe) ----
// xp is 512 KB: [0, 524288). NOTHING else may live below OFFB_K2 (R6 lesson: alias -> NaN).
#define OFFB_XP    0u
#define OFFB_K2    524288u            // after k_attn: bf16 weights (Wproj@0, Wa1@16384, Wa2@20480 shorts)
#define OFFB_V2    786432u
#define OFFB_QKVG  (1u << 20)         // bf16 (b,256,HW): 0-63 q, 64-127 k, 128-191 v, 192-255 qg->res_l
#define OFFB_RESH  (33u << 20)        // bf16 (b,64,HW); first 64KB = conv weights bf16 until k_resh
// p / v-hat scratch in d_out [0,16MiB); d_out fully overwritten by k_proj.

// ---------------- 8x8 avgpool + conv-weight bf16 preconvert (blocks 0-7) ----------------
__global__ __launch_bounds__(256) void k_pool(const float* __restrict__ x, float* __restrict__ xp,
                                              const float* __restrict__ Wqkv, const float* __restrict__ Wq,
                                              short* __restrict__ wconv)
{
    int idx = blockIdx.x * 256 + threadIdx.x;
    int j = idx & 15, i = (idx >> 4) & 15, bc = idx >> 8;
    const float* src = x + (size_t)bc * HW + (i * 8) * 128 + j * 8;
    float s = 0.f;
    #pragma unroll
    for (int u = 0; u < 8; u++) {
        #pragma unroll
        for (int t = 0; t < 8; t++) s += src[u * 128 + t];
    }
    xp[bc * 256 + i * 16 + j] = s * (1.f / 64.f);

    if (blockIdx.x < 8) {               // convert 32768 conv-weight floats -> bf16 (256x128 row-major)
        int base = blockIdx.x * 4096 + threadIdx.x * 16;
        #pragma unroll
        for (int e = 0; e < 16; e += 4) {
            int k = base + e;
            const float* ws = (k < 24576) ? (Wqkv + k) : (Wq + k - 24576);
            floatx4 wv = *(const floatx4*)ws;
            short4v pk;
            pk[0] = f2bs(wv[0]); pk[1] = f2bs(wv[1]); pk[2] = f2bs(wv[2]); pk[3] = f2bs(wv[3]);
            *(short4v*)&wconv[k] = pk;
        }
    }
}

// ---------------- kv conv: xp -> k2/v2 fp32 (b,h,m,d). grid (4b x 128o) = 512 ------------
// R7 fix: one (b,o) per block, Wkv row in LDS, 128 independent coalesced loads.
// Partial-sum order bit-identical to original.
__global__ __launch_bounds__(256) void k_kv(const float* __restrict__ xp,
                                            const float* __restrict__ Wkv, const float* __restrict__ bkv,
                                            float* __restrict__ k2, float* __restrict__ v2)
{
    __shared__ float w_s[128];
    int o = blockIdx.x & 127, b = blockIdx.x >> 7;
    int m = threadIdx.x;
    if (m < 128) w_s[m] = Wkv[o * 128 + m];
    __syncthreads();
    const float* xb = xp + b * 32768 + m;
    float s0 = 0.f, s1 = 0.f, s2 = 0.f, s3 = 0.f;
    #pragma unroll
    for (int c = 0; c < 128; c += 4) {
        s0 += w_s[c]     * xb[(size_t)(c)     * 256];
        s1 += w_s[c + 1] * xb[(size_t)(c + 1) * 256];
        s2 += w_s[c + 2] * xb[(size_t)(c + 2) * 256];
        s3 += w_s[c + 3] * xb[(size_t)(c + 3) * 256];
    }
    float a = bkv[o] + ((s0 + s1) + (s2 + s3));
    int sb = o >> 6, r = o & 63, gh = r >> 4, dh = r & 15;
    float* dst = sb == 0 ? k2 : v2;
    dst[((b * 4 + gh) * 256 + m) * 16 + dh] = a;
}

// ------- MFMA conv1x1: x -> qkvg bf16. grid (64 px-pairs, 2 m-blocks, 4 b); 2 subtiles ---
// B staging conflict-free: thread owns one px (t&127), gathers 8 consecutive channels
// (coalesced dword loads), writes ONE contiguous ds_write_b128 into the packed slot.
__global__ __launch_bounds__(256) void k_conv(const float* __restrict__ x,
                                              const short* __restrict__ wconv,
                                              const float* __restrict__ bqkv, const float* __restrict__ bq,
                                              bf16* __restrict__ qkvg)
{
    __shared__ short a_s[128 * 128];          // A[oc][k] bf16
    __shared__ short b_s[128 * 128];          // B packed [k>>3][px][k&7] bf16
    __shared__ float bias_s[128];
    int t = threadIdx.x;
    int b = blockIdx.z, my = blockIdx.y;
    int px0b = blockIdx.x * 256;

    if (t < 128) {
        int oc = my * 128 + t;
        bias_s[t] = (oc < 192) ? bqkv[oc] : bq[oc - 192];
    }
    const short* wsrc = wconv + my * 16384;   // rows my*128..my*128+127, row-major
    #pragma unroll
    for (int i = 0; i < 8; i++) {             // stage A: bf16 copy
        int idx = i * 2048 + t * 8;
        *(short8v*)&a_s[idx] = *(const short8v*)&wsrc[idx];
    }

    int wave = wuniform(t >> 6);
    int lane = t & 63;
    int quad = lane >> 4, l16 = lane & 15;
    int pxs = t & 127, chalf = (t >> 7) * 64;

    #pragma unroll 1
    for (int sub = 0; sub < 2; sub++) {
        int px0 = px0b + sub * 128;
        const float* xb = x + (size_t)b * 128 * HW + px0 + pxs;
        #pragma unroll
        for (int p = 0; p < 8; p++) {         // stage B: 8 coalesced loads -> 1 b128 write
            int c0 = chalf + p * 8;
            float xv[8];
            #pragma unroll
            for (int jj = 0; jj < 8; jj++) xv[jj] = xb[(size_t)(c0 + jj) * HW];
            short8v pk;
            #pragma unroll
            for (int jj = 0; jj < 8; jj++) pk[jj] = f2bs(xv[jj]);
            *(short8v*)&b_s[((c0 >> 3) * 128 + pxs) * 8] = pk;
        }
        __syncthreads();

        floatx4 acc[2][8] = {};
        #pragma unroll
        for (int kk = 0; kk < 4; kk++) {
            short8v a0 = *(const short8v*)&a_s[(wave * 32 + l16) * 128 + kk * 32 + quad * 8];
            short8v a1 = *(const short8v*)&a_s[(wave * 32 + 16 + l16) * 128 + kk * 32 + quad * 8];
            #pragma unroll
            for (int nt = 0; nt < 8; nt++) {
                short8v bv = *(const short8v*)&b_s[((kk * 4 + quad) * 128 + nt * 16 + l16) * 8];
                acc[0][nt] = __builtin_amdgcn_mfma_f32_16x16x32_bf16(a0, bv, acc[0][nt], 0, 0, 0);
                acc[1][nt] = __builtin_amdgcn_mfma_f32_16x16x32_bf16(a1, bv, acc[1][nt], 0, 0, 0);
            }
        }
        #pragma unroll
        for (int m = 0; m < 2; m++) {
            int rowb = wave * 32 + m * 16 + quad * 4;
            #pragma unroll
            for (int nt = 0; nt < 8; nt++) {
                int px = px0 + nt * 16 + l16;
                #pragma unroll
                for (int r = 0; r < 4; r++) {
                    int row = rowb + r;
                    float val = acc[m][nt][r] + bias_s[row];
                    qkvg[((size_t)b * 256 + my * 128 + row) * HW + px] = f2b(val);
                }
            }
        }
        __syncthreads();                      // MFMA reads done before next-sub B restage
    }
}

// ---------------- depthwise 3x3 + q*k, vectorized: 8 px/thread. grid 2048 ----------------
__global__ __launch_bounds__(256) void k_dw(const bf16* __restrict__ qkvg,
                                            const float* __restrict__ Wdw, const float* __restrict__ bdw,
                                            bf16* __restrict__ p, bf16* __restrict__ v)
{
    int blk = blockIdx.x;            // 2048
    int bc = blk >> 3;               // b*64+c
    int c = bc & 63, b = bc >> 6;
    int g = (blk & 7) * 256 + threadIdx.x;   // 0..2047 pixel-groups in plane
    int i = g >> 4;                  // row
    int j0 = (g & 15) * 8;           // col start
    float acc[3][8];
    #pragma unroll
    for (int pl = 0; pl < 3; pl++) {
        float bias = bdw[pl * 64 + c];
        #pragma unroll
        for (int t2 = 0; t2 < 8; t2++) acc[pl][t2] = bias;
    }
    #pragma unroll
    for (int pl = 0; pl < 3; pl++) {
        const bf16* plane = qkvg + (size_t)(b * 256 + pl * 64 + c) * HW;
        const float* w = Wdw + (pl * 64 + c) * 9;
        #pragma unroll
        for (int dy = 0; dy < 3; dy++) {
            int ii = i + dy - 1;
            float e[10];
            if ((unsigned)ii < 128u) {
                const bf16* r = plane + ii * 128 + j0;
                short8v v8 = *(const short8v*)r;
                #pragma unroll
                for (int t2 = 0; t2 < 8; t2++) e[t2 + 1] = bs2f(v8[t2]);
                e[0] = (j0 > 0) ? b2f(r[-1]) : 0.f;
                e[9] = (j0 < 120) ? b2f(r[8]) : 0.f;
            } else {
                #pragma unroll
                for (int t2 = 0; t2 < 10; t2++) e[t2] = 0.f;
            }
            float wa = w[dy * 3], wb = w[dy * 3 + 1], wc = w[dy * 3 + 2];
            #pragma unroll
            for (int t2 = 0; t2 < 8; t2++)
                acc[pl][t2] += wa * e[t2] + wb * e[t2 + 1] + wc * e[t2 + 2];
        }
    }
    short8v pv, vv;
    #pragma unroll
    for (int t2 = 0; t2 < 8; t2++) {
        pv[t2] = f2bs(acc[0][t2] * acc[1][t2]);
        vv[t2] = f2bs(acc[2][t2]);
    }
    size_t off = (size_t)(b * 64 + c) * HW + i * 128 + j0;
    *(short8v*)(p + off) = pv;
    *(short8v*)(v + off) = vv;
}

// ---------------- MFMA low-freq attention. grid (256 px-blocks, 4 h, 4 b), 256 thr ------
// In-register P (proven R4). R11: 64 px/block (was 256) -> grid 4096, LDS 28 KiB ->
// 5 blocks/CU resident vs 16 blocks/CU of work = 3.2 scheduling rounds. Later blocks'
// staging overlaps earlier blocks' compute (R10 showed the stalls are phase-synchronized,
// not TLP-coverable: one wave-round = all waves stage/compute in lockstep). K/V staged 4x
// per (b,h) (L2/L3-resident, ~3us cost). Arithmetic bit-identical; 1 pxt per wave.
__global__ __launch_bounds__(256, 5) void k_attn(bf16* __restrict__ qkvg, const float* __restrict__ k2,
                                                 const float* __restrict__ v2)
{
    __shared__ short kt[16 * 64 * 8];   // 16 KiB: K A-frags (key-permuted), k=16..31 zero
    __shared__ short vt[8 * 64 * 8];    // 8 KiB: V frags (A-role: V^T)
    __shared__ short un[4 * 64 * 8];    // 4 KiB: Q B-frag staging (4 pxt)
    int t = threadIdx.x;
    int h = blockIdx.y, b = blockIdx.z;
    int px0b = blockIdx.x * 64;
    const float* K = k2 + (size_t)(b * 4 + h) * 4096;
    const float* V = v2 + (size_t)(b * 4 + h) * 4096;
    bf16* Qbase = qkvg + (size_t)(b * 256 + 192 + h * 16) * HW + px0b;

    {
        int mb = t >> 5, kl = t & 31, q = kl >> 3, s = kl & 7;
        int tile = 2 * mb + (s >> 2), row = q * 4 + (s & 3);
        float4 k0 = *(const float4*)(K + t * 16);
        float4 k1 = *(const float4*)(K + t * 16 + 4);
        float4 kx2 = *(const float4*)(K + t * 16 + 8);
        float4 k3 = *(const float4*)(K + t * 16 + 12);
        short8v lo, hi, zz = {};
        lo[0] = f2bs(k0.x); lo[1] = f2bs(k0.y); lo[2] = f2bs(k0.z); lo[3] = f2bs(k0.w);
        lo[4] = f2bs(k1.x); lo[5] = f2bs(k1.y); lo[6] = f2bs(k1.z); lo[7] = f2bs(k1.w);
        hi[0] = f2bs(kx2.x); hi[1] = f2bs(kx2.y); hi[2] = f2bs(kx2.z); hi[3] = f2bs(kx2.w);
        hi[4] = f2bs(k3.x); hi[5] = f2bs(k3.y); hi[6] = f2bs(k3.z); hi[7] = f2bs(k3.w);
        *(short8v*)&kt[(tile * 64 + row) * 8] = lo;
        *(short8v*)&kt[(tile * 64 + 16 + row) * 8] = hi;
        *(short8v*)&kt[(tile * 64 + 32 + row) * 8] = zz;
        *(short8v*)&kt[(tile * 64 + 48 + row) * 8] = zz;
    }
    #pragma unroll
    for (int u = 0; u < 2; u++) {           // 512 V frags, two per thread
        int f = t * 2 + u;
        int mb = f >> 6, lane = f & 63, quad = lane >> 4, d = lane & 15;
        short8v pk;
        #pragma unroll
        for (int i = 0; i < 8; i++) pk[i] = f2bs(V[(mb * 32 + quad * 8 + i) * 16 + d]);
        *(short8v*)&vt[f * 8] = pk;
    }
    {
        int f = t;                          // 256 Q frags (4 pxt x 64), one per thread
        int pxt = f >> 6, lane = f & 63, quad = lane >> 4, l16 = lane & 15;
        int px = pxt * 16 + l16;
        short8v pk = {};
        if (quad < 2) {
            #pragma unroll
            for (int i = 0; i < 8; i++)   // 0.25 (= dh^-0.5) * log2(e) folded in
                pk[i] = f2bs(b2f(Qbase[(size_t)(quad * 8 + i) * HW + px]) * 0.36067376022224085f);
        }
        *(short8v*)&un[f * 8] = pk;
    }
    __syncthreads();

    int wave = wuniform(t >> 6);            // 0..3, = this wave's pxt
    int lane = t & 63;
    int quad = lane >> 4, l16 = lane & 15;
    short8v qf = *(const short8v*)&un[(wave * 64 + lane) * 8];

    {
        int pxt = wave;
        floatx4 denv = {};
        floatx4 oa = {};
        #pragma unroll
        for (int mb = 0; mb < 8; mb++) {
            short8v kfE = *(const short8v*)&kt[((2 * mb) * 64 + lane) * 8];
            short8v kfO = *(const short8v*)&kt[((2 * mb + 1) * 64 + lane) * 8];
            floatx4 scE = __builtin_amdgcn_mfma_f32_16x16x32_bf16(kfE, qf, (floatx4){0.f, 0.f, 0.f, 0.f}, 0, 0, 0);
            floatx4 scO = __builtin_amdgcn_mfma_f32_16x16x32_bf16(kfO, qf, (floatx4){0.f, 0.f, 0.f, 0.f}, 0, 0, 0);
            floatx4 peE, peO;
            #pragma unroll
            for (int r = 0; r < 4; r++) {
                peE[r] = exp2f(fminf(scE[r], 86.f));
                peO[r] = exp2f(fminf(scO[r], 86.f));
            }
            denv += peE;
            denv += peO;
            short8v pa;
            pa[0] = f2bs(peE[0]); pa[1] = f2bs(peE[1]); pa[2] = f2bs(peE[2]); pa[3] = f2bs(peE[3]);
            pa[4] = f2bs(peO[0]); pa[5] = f2bs(peO[1]); pa[6] = f2bs(peO[2]); pa[7] = f2bs(peO[3]);
            short8v vf = *(const short8v*)&vt[(mb * 64 + lane) * 8];
            oa = __builtin_amdgcn_mfma_f32_16x16x32_bf16(vf, pa, oa, 0, 0, 0);
        }
        float den = (denv[0] + denv[1]) + (denv[2] + denv[3]);
        den += __shfl_xor(den, 16, 64);
        den += __shfl_xor(den, 32, 64);
        float rden = 1.f / den;
        #pragma unroll
        for (int r = 0; r < 4; r++)
            Qbase[(size_t)(quad * 4 + r) * HW + pxt * 16 + l16] = f2b(oa[r] * rden);
    }
}

// ---------------- late-weight bf16 preconvert: Wproj/Wa1/Wa2 -> k2 region (dead) ---------
__global__ __launch_bounds__(256) void k_wcvt(const float* __restrict__ Wproj,
                                              const float* __restrict__ Wa1, const float* __restrict__ Wa2,
                                              short* __restrict__ wdst)
{
    int idx = blockIdx.x * 1024 + threadIdx.x * 4;   // 24 blocks -> 24576 floats
    const float* src;
    if (idx < 16384)      src = Wproj + idx;
    else if (idx < 20480) src = Wa1 + (idx - 16384);
    else                  src = Wa2 + (idx - 20480);
    floatx4 wv = *(const floatx4*)src;
    short4v pk;
    pk[0] = f2bs(wv[0]); pk[1] = f2bs(wv[1]); pk[2] = f2bs(wv[2]); pk[3] = f2bs(wv[3]);
    *(short4v*)&wdst[idx] = pk;
}

// ---------------- MFMA high-freq gate: p,v-hat -> res_h. grid (128 px-tiles, 4 b) --------
// GEMM1 (Wa1 64x64 · P) -> swish -> repack -> GEMM2 (Wa2 64x64) -> tanh*vhat
// bp staging conflict-free: per-thread px, 8-channel gather -> 1 b128 write.
__global__ __launch_bounds__(256) void k_resh(const bf16* __restrict__ p, const bf16* __restrict__ vhat,
                                              const short* __restrict__ wabf,
                                              const float* __restrict__ ba1, const float* __restrict__ ba2,
                                              bf16* __restrict__ resh)
{
    __shared__ short aw1[64 * 64];       // A1[oc][ic]
    __shared__ short aw2[64 * 64];       // A2[oc][ic]
    __shared__ short bp[8 * 128 * 8];    // P  packed [ic>>3][px][ic&7]
    __shared__ short bs2[8 * 128 * 8];   // swish packed (same layout)
    __shared__ float b1s[64], b2s[64];
    int t = threadIdx.x;
    int b = blockIdx.y;
    int px0 = blockIdx.x * 128;

    if (t < 64) { b1s[t] = ba1[t]; b2s[t] = ba2[t]; }
    #pragma unroll
    for (int i = 0; i < 2; i++) {        // stage Wa1/Wa2 (bf16 pre-converted)
        int idx = i * 2048 + t * 8;
        *(short8v*)&aw1[idx] = *(const short8v*)&wabf[idx];
        *(short8v*)&aw2[idx] = *(const short8v*)&wabf[4096 + idx];
    }
    {
        int pxs = t & 127, chalf = (t >> 7) * 32;
        const short* pb = (const short*)p + (size_t)b * 64 * HW + px0 + pxs;
        #pragma unroll
        for (int pp = 0; pp < 4; pp++) {  // stage P: 8-channel gather -> b128 write
            int c0 = chalf + pp * 8;
            short8v pk;
            #pragma unroll
            for (int jj = 0; jj < 8; jj++) pk[jj] = pb[(size_t)(c0 + jj) * HW];
            *(short8v*)&bp[((c0 >> 3) * 128 + pxs) * 8] = pk;
        }
    }
    __syncthreads();

    int wave = wuniform(t >> 6);         // = mtile (M=64 -> 4 mtiles)
    int lane = t & 63;
    int quad = lane >> 4, l16 = lane & 15;
    int k0 = wave * 16 + quad * 4;       // output-channel base for this lane's C rows

    floatx4 acc1[8] = {};
    #pragma unroll
    for (int kk = 0; kk < 2; kk++) {
        short8v af = *(const short8v*)&aw1[(wave * 16 + l16) * 64 + kk * 32 + quad * 8];
        #pragma unroll
        for (int nt = 0; nt < 8; nt++) {
            short8v bf = *(const short8v*)&bp[((kk * 4 + quad) * 128 + nt * 16 + l16) * 8];
            acc1[nt] = __builtin_amdgcn_mfma_f32_16x16x32_bf16(af, bf, acc1[nt], 0, 0, 0);
        }
    }
    #pragma unroll
    for (int nt = 0; nt < 8; nt++) {     // swish + repack C-layout -> B-frag layout
        int px = nt * 16 + l16;
        short4v pk;
        #pragma unroll
        for (int r = 0; r < 4; r++) {
            float a = acc1[nt][r] + b1s[k0 + r];
            pk[r] = f2bs(a / (1.f + __expf(-a)));
        }
        *(short4v*)&bs2[((k0 >> 3) * 128 + px) * 8 + (k0 & 7)] = pk;
    }
    __syncthreads();

    floatx4 acc2[8] = {};
    #pragma unroll
    for (int kk = 0; kk < 2; kk++) {
        short8v af = *(const short8v*)&aw2[(wave * 16 + l16) * 64 + kk * 32 + quad * 8];
        #pragma unroll
        for (int nt = 0; nt < 8; nt++) {
            short8v bf = *(const short8v*)&bs2[((kk * 4 + quad) * 128 + nt * 16 + l16) * 8];
            acc2[nt] = __builtin_amdgcn_mfma_f32_16x16x32_bf16(af, bf, acc2[nt], 0, 0, 0);
        }
    }
    #pragma unroll
    for (int nt = 0; nt < 8; nt++) {
        int px = px0 + nt * 16 + l16;
        #pragma unroll
        for (int r = 0; r < 4; r++) {
            int oc = k0 + r;
            float g = tanhf((acc2[nt][r] + b2s[oc]) * 0.25f);
            float vv = b2f(vhat[(size_t)(b * 64 + oc) * HW + px]);
            resh[(size_t)(b * 64 + oc) * HW + px] = f2b(g * vv);
        }
    }
}

// ---------------- MFMA final proj: [res_h|res_l] -> out fp32. grid (128 px-tiles, 4 b) ---
// B staging conflict-free: per-thread px, 8-channel gather -> 1 b128 write.
__global__ __launch_bounds__(256) void k_proj(const bf16* __restrict__ resh, const bf16* __restrict__ qkvg,
                                              const short* __restrict__ wpbf, const float* __restrict__ bproj,
                                              float* __restrict__ out)
{
    __shared__ short a_s[128 * 128];
    __shared__ short b_s[128 * 128];
    __shared__ float bias_s[128];
    int t = threadIdx.x;
    int b = blockIdx.y;
    int px0 = blockIdx.x * 128;
    const bf16* resl = qkvg + (size_t)(b * 256 + 192) * HW;

    if (t < 128) bias_s[t] = bproj[t];
    #pragma unroll
    for (int i = 0; i < 8; i++) {        // stage A (Wproj bf16 pre-converted)
        int idx = i * 2048 + t * 8;
        *(short8v*)&a_s[idx] = *(const short8v*)&wpbf[idx];
    }
    {
        int pxs = t & 127, half = t >> 7;
        const short* srcb = half == 0 ? ((const short*)resh + (size_t)b * 64 * HW + px0 + pxs)
                                      : ((const short*)resl + px0 + pxs);
        #pragma unroll
        for (int pp = 0; pp < 8; pp++) {  // stage B: 8-channel gather -> b128 write
            int c0 = half * 64 + pp * 8;
            short8v pk;
            #pragma unroll
            for (int jj = 0; jj < 8; jj++) pk[jj] = srcb[(size_t)(pp * 8 + jj) * HW];
            *(short8v*)&b_s[((c0 >> 3) * 128 + pxs) * 8] = pk;
        }
    }
    __syncthreads();

    int wave = wuniform(t >> 6);
    int lane = t & 63;
    int quad = lane >> 4, l16 = lane & 15;
    floatx4 acc[2][8] = {};
    #pragma unroll
    for (int kk = 0; kk < 4; kk++) {
        short8v a0 = *(const short8v*)&a_s[(wave * 32 + l16) * 128 + kk * 32 + quad * 8];
        short8v a1 = *(const short8v*)&a_s[(wave * 32 + 16 + l16) * 128 + kk * 32 + quad * 8];
        #pragma unroll
        for (int nt = 0; nt < 8; nt++) {
            short8v bv = *(const short8v*)&b_s[((kk * 4 + quad) * 128 + nt * 16 + l16) * 8];
            acc[0][nt] = __builtin_amdgcn_mfma_f32_16x16x32_bf16(a0, bv, acc[0][nt], 0, 0, 0);
            acc[1][nt] = __builtin_amdgcn_mfma_f32_16x16x32_bf16(a1, bv, acc[1][nt], 0, 0, 0);
        }
    }
    #pragma unroll
    for (int m = 0; m < 2; m++) {
        int rowb = wave * 32 + m * 16 + quad * 4;
        #pragma unroll
        for (int nt = 0; nt < 8; nt++) {
            int px = px0 + nt * 16 + l16;
            #pragma unroll
            for (int r = 0; r < 4; r++) {
                int row = rowb + r;
                out[((size_t)b * 128 + row) * HW + px] = acc[m][nt][r] + bias_s[row];
            }
        }
    }
}

extern "C" void kernel_launch(void* const* d_in, const int* in_sizes, int n_in,
                              void* d_out, int out_size, void* d_ws, size_t ws_size,
                              hipStream_t stream)
{
    (void)in_sizes; (void)n_in; (void)out_size; (void)ws_size;
    const float* x     = (const float*)d_in[0];
    const float* Wqkv  = (const float*)d_in[1];
    const float* bqkv  = (const float*)d_in[2];
    const float* Wdw   = (const float*)d_in[3];
    const float* bdw   = (const float*)d_in[4];
    const float* Wa1   = (const float*)d_in[5];
    const float* ba1   = (const float*)d_in[6];
    const float* Wa2   = (const float*)d_in[7];
    const float* ba2   = (const float*)d_in[8];
    const float* Wq    = (const float*)d_in[9];
    const float* bq    = (const float*)d_in[10];
    const float* Wkv   = (const float*)d_in[11];
    const float* bkv   = (const float*)d_in[12];
    const float* Wproj = (const float*)d_in[13];
    const float* bproj = (const float*)d_in[14];

    char* wsb = (char*)d_ws;
    float* xp   = (float*)(wsb + OFFB_XP);
    float* k2   = (float*)(wsb + OFFB_K2);
    float* v2   = (float*)(wsb + OFFB_V2);
    bf16*  qkvg = (bf16*)(wsb + OFFB_QKVG);
    bf16*  resh = (bf16*)(wsb + OFFB_RESH);
    short* wconv = (short*)(wsb + OFFB_RESH); // conv weights bf16; dead before k_resh writes
    short* wlate = (short*)(wsb + OFFB_K2);   // Wproj/Wa bf16; k2 dead after k_attn
    bf16*  p    = (bf16*)d_out;               // scratch in d_out, dead before k_proj
    bf16*  v    = (bf16*)d_out + 4194304;
    float* out  = (float*)d_out;

    k_pool<<<dim3(512), 256, 0, stream>>>(x, xp, Wqkv, Wq, wconv);
    k_kv<<<dim3(512), 256, 0, stream>>>(xp, Wkv, bkv, k2, v2);
    k_conv<<<dim3(64, 2, 4), 256, 0, stream>>>(x, wconv, bqkv, bq, qkvg);
    k_dw<<<dim3(2048), 256, 0, stream>>>(qkvg, Wdw, bdw, p, v);
    k_attn<<<dim3(256, 4, 4), 256, 0, stream>>>(qkvg, k2, v2);      // res_l in-place over qg ch
    k_wcvt<<<dim3(24), 256, 0, stream>>>(Wproj, Wa1, Wa2, wlate);
    k_resh<<<dim3(128, 4), 256, 0, stream>>>(p, v, wlate + 16384, ba1, ba2, resh);
    k_proj<<<dim3(128, 4), 256, 0, stream>>>(resh, qkvg, wlate, bproj, out);
}